// Round 3
// baseline (275.517 us; speedup 1.0000x reference)
//
#include <hip/hip_runtime.h>
#include <math.h>

#define NPOS 110592

typedef float f32x4 __attribute__((ext_vector_type(4)));
typedef short bf16x8 __attribute__((ext_vector_type(8)));
typedef unsigned u32;
typedef u32 u32x4 __attribute__((ext_vector_type(4)));

#define MFMA __builtin_amdgcn_mfma_f32_16x16x32_bf16

__device__ __forceinline__ short f2bf(float f) {
    u32 u = __builtin_bit_cast(u32, f);
    u += 0x7fffu + ((u >> 16) & 1u);
    return (short)(u >> 16);
}
__device__ __forceinline__ u32 pack2(float a, float b) {
    return (u32)(unsigned short)f2bf(a) | ((u32)(unsigned short)f2bf(b) << 16);
}

union FragU { u32 w[4]; bf16x8 v; };

// In-register transpose: two C-layout tiles (16 rows each, rows = future K) ->
// one A/B fragment for a K=32 MFMA. Source pk*[2] are pack2(acc0,acc1),pack2(acc2,acc3).
// Derivation: target lane (g,m), u32 q holds k=2q,2q+1; k = g*8+j ->
// src tile = g>>1 (register select), src lane = ((g&1)*2 + (q>>1))*16 + m, src u32 = q&1.
__device__ __forceinline__ bf16x8 xpose(const u32* pk0, const u32* pk1, int g, int m) {
    int s0 = ((((g & 1) * 2 + 0) * 16 + m) << 2);
    int s1 = ((((g & 1) * 2 + 1) * 16 + m) << 2);
    u32 a0 = (u32)__builtin_amdgcn_ds_bpermute(s0, (int)pk0[0]);
    u32 a1 = (u32)__builtin_amdgcn_ds_bpermute(s0, (int)pk0[1]);
    u32 a2 = (u32)__builtin_amdgcn_ds_bpermute(s1, (int)pk0[0]);
    u32 a3 = (u32)__builtin_amdgcn_ds_bpermute(s1, (int)pk0[1]);
    u32 b0 = (u32)__builtin_amdgcn_ds_bpermute(s0, (int)pk1[0]);
    u32 b1 = (u32)__builtin_amdgcn_ds_bpermute(s0, (int)pk1[1]);
    u32 b2 = (u32)__builtin_amdgcn_ds_bpermute(s1, (int)pk1[0]);
    u32 b3 = (u32)__builtin_amdgcn_ds_bpermute(s1, (int)pk1[1]);
    bool hi = g >= 2;
    FragU f;
    f.w[0] = hi ? b0 : a0;
    f.w[1] = hi ? b1 : a1;
    f.w[2] = hi ? b2 : a2;
    f.w[3] = hi ? b3 : a3;
    return f.v;
}

// ---- prep: fp32 weights -> bf16 ----
__global__ __launch_bounds__(256) void la_prep(const float* __restrict__ wqkv,
                                               const float* __restrict__ wout,
                                               short* __restrict__ wqkv_bf,
                                               short* __restrict__ wout_bf)
{
    int i = blockIdx.x * 256 + threadIdx.x;
    if (i < 24576) wqkv_bf[i] = f2bf(wqkv[i]);
    if (i < 8192)  wout_bf[i] = f2bf(wout[i]);
}

// ---- pass1: rmsnorm -> (store Xn frags) -> K,V GEMM -> exp -> in-reg transpose -> ctx partial ----
// MODE 0: big ws (write xn frags + per-block partials). MODE 1: global atomics, no frags.
template<int MODE>
__global__ __launch_bounds__(256, 4) void la_pass1(
    const float* __restrict__ x, const float* __restrict__ g_in,
    const short* __restrict__ wkv,
    short* __restrict__ xnfrag, float* __restrict__ partials,
    float* __restrict__ ctxG, float* __restrict__ zG)
{
    __shared__ float ctxZone[4096];
    __shared__ float zZone[128];
    __shared__ __align__(16) char xnz[4][4096];

    const int tid = threadIdx.x;
    const int lane = tid & 63, wid = tid >> 6;
    const int g = (lane >> 4) & 3, m = lane & 15;
    const int blk = blockIdx.x;
    const int batch = blk / 432, cb = blk % 432;

    for (int i = tid; i < 4096; i += 256) ctxZone[i] = 0.f;
    if (tid < 128) zZone[tid] = 0.f;
    __syncthreads();

    char* zn = xnz[wid];

#pragma unroll 1
    for (int ic = 0; ic < 2; ++ic) {
        const int cq = wid * 2 + ic;                 // chunk index within block (0..7)
        const int posbase = cb * 256 + cq * 32;

        // ---- load + rmsnorm (2 lanes per position: 32 channels each) ----
        const int p = lane & 31, chb = (lane >> 5) * 32;
        const float* xb = x + ((size_t)batch * 64 + chb) * NPOS + posbase + p;
        float xv[32]; float ss = 0.f;
#pragma unroll
        for (int c = 0; c < 32; ++c) { float t = xb[(size_t)c * NPOS]; xv[c] = t; ss += t * t; }
        ss += __shfl_xor(ss, 32);
        float rn = 8.0f / fmaxf(sqrtf(ss), 1e-12f);
#pragma unroll
        for (int c = 0; c < 32; ++c) xv[c] *= rn * g_in[chb + c];

        // ---- stage [32 p][64 c] bf16, 16B-chunk XOR swizzle ----
#pragma unroll
        for (int qq = 0; qq < 4; ++qq) {
            u32x4 w;
            w.x = pack2(xv[qq*8+0], xv[qq*8+1]);
            w.y = pack2(xv[qq*8+2], xv[qq*8+3]);
            w.z = pack2(xv[qq*8+4], xv[qq*8+5]);
            w.w = pack2(xv[qq*8+6], xv[qq*8+7]);
            int chunk = (lane >> 5) * 4 + qq;
            *(u32x4*)(zn + p * 128 + ((chunk ^ (p & 7)) << 4)) = w;
        }
        asm volatile("s_waitcnt lgkmcnt(0)" ::: "memory");

        bf16x8 af[2][2];
#pragma unroll
        for (int mt = 0; mt < 2; ++mt)
#pragma unroll
            for (int kf = 0; kf < 2; ++kf) {
                int row = mt * 16 + m;
                af[mt][kf] = *(const bf16x8*)(zn + row * 128 + (((kf*4+g) ^ (row & 7)) << 4));
            }

        if constexpr (MODE == 0) {
            const int slot = batch * 3456 + cb * 8 + cq;
#pragma unroll
            for (int f = 0; f < 4; ++f)
                *(bf16x8*)(xnfrag + ((size_t)(slot * 4 + f) * 64 + lane) * 8) = af[f >> 1][f & 1];
        }

#pragma unroll 1
        for (int h = 0; h < 4; ++h) {
            u32 ekpk[2][2][2], vpk[2][2][2];
#pragma unroll
            for (int nt2 = 0; nt2 < 2; ++nt2) {
                const short* wr = wkv + (size_t)(128 + h*32 + nt2*16 + m) * 64 + g * 8;
                bf16x8 w0 = *(const bf16x8*)wr;
                bf16x8 w1 = *(const bf16x8*)(wr + 32);
                float zl = 0.f;
#pragma unroll
                for (int mt = 0; mt < 2; ++mt) {
                    f32x4 a = {0.f, 0.f, 0.f, 0.f};
                    a = MFMA(af[mt][0], w0, a, 0, 0, 0);
                    a = MFMA(af[mt][1], w1, a, 0, 0, 0);
                    float e0 = __expf(a[0]), e1 = __expf(a[1]);
                    float e2 = __expf(a[2]), e3 = __expf(a[3]);
                    zl += (e0 + e1) + (e2 + e3);
                    ekpk[nt2][mt][0] = pack2(e0, e1);
                    ekpk[nt2][mt][1] = pack2(e2, e3);
                }
                atomicAdd(&zZone[h*32 + nt2*16 + m], zl);
            }
#pragma unroll
            for (int nt2 = 0; nt2 < 2; ++nt2) {
                const short* wr = wkv + (size_t)(256 + h*32 + nt2*16 + m) * 64 + g * 8;
                bf16x8 w0 = *(const bf16x8*)wr;
                bf16x8 w1 = *(const bf16x8*)(wr + 32);
#pragma unroll
                for (int mt = 0; mt < 2; ++mt) {
                    f32x4 a = {0.f, 0.f, 0.f, 0.f};
                    a = MFMA(af[mt][0], w0, a, 0, 0, 0);
                    a = MFMA(af[mt][1], w1, a, 0, 0, 0);
                    vpk[nt2][mt][0] = pack2(a[0], a[1]);
                    vpk[nt2][mt][1] = pack2(a[2], a[3]);
                }
            }
            bf16x8 afr[2], bfr[2];
#pragma unroll
            for (int t2 = 0; t2 < 2; ++t2) {
                afr[t2] = xpose(ekpk[t2][0], ekpk[t2][1], g, m);
                bfr[t2] = xpose(vpk[t2][0], vpk[t2][1], g, m);
            }
#pragma unroll
            for (int D = 0; D < 2; ++D)
#pragma unroll
                for (int E = 0; E < 2; ++E) {
                    f32x4 cc = {0.f, 0.f, 0.f, 0.f};
                    cc = MFMA(afr[D], bfr[E], cc, 0, 0, 0);
#pragma unroll
                    for (int r = 0; r < 4; ++r)
                        atomicAdd(&ctxZone[h*1024 + (D*16 + g*4 + r)*32 + E*16 + m], cc[r]);
                }
        }
    }
    __syncthreads();

    if constexpr (MODE == 0) {
        float* P = partials + (size_t)blk * 4224;
        for (int i = tid; i < 4096; i += 256) P[i] = ctxZone[i];
        if (tid < 128) P[4096 + tid] = zZone[tid];
    } else {
        float* cg = ctxG + batch * 4096;
        for (int i = tid; i < 4096; i += 256) atomicAdd(&cg[i], ctxZone[i]);
        if (tid < 128) atomicAdd(&zG[batch * 128 + tid], zZone[tid]);
    }
}

// ---- reduce per-block partials -> ctxG, zG ----
__global__ __launch_bounds__(256) void la_reduce(const float* __restrict__ partials,
                                                 float* __restrict__ ctxG,
                                                 float* __restrict__ zG)
{
    int t = blockIdx.x * 256 + threadIdx.x;
    if (t >= 8448) return;
    int b = t / 4224, i = t % 4224;
    const float* P = partials + (size_t)b * 432 * 4224 + i;
    float s = 0.f;
    for (int j = 0; j < 432; ++j) s += P[(size_t)j * 4224];
    if (i < 4096) ctxG[b * 4096 + i] = s;
    else          zG[b * 128 + (i - 4096)] = s;
}

// ---- fold mem_kv, normalize, write ctxT[b][h][e][d] bf16 ----
__global__ __launch_bounds__(256) void la_ctxt(const float* __restrict__ ctxG,
                                               const float* __restrict__ zG,
                                               const float* __restrict__ mem_kv,
                                               short* __restrict__ ctxT)
{
    int t = blockIdx.x * 256 + threadIdx.x;
    if (t >= 8192) return;
    int b = t >> 12, r = t & 4095, h = r >> 10, de = r & 1023, e = de >> 5, d = de & 31;
    float S = ctxG[b*4096 + h*1024 + d*32 + e];
    float Z = zG[b*128 + h*32 + d];
    const float* mk = mem_kv + (h*32 + d) * 4;
    const float* mv = mem_kv + 512 + (h*32 + e) * 4;
#pragma unroll
    for (int mm = 0; mm < 4; ++mm) {
        float ek = __expf(mk[mm]);
        S += ek * mv[mm];
        Z += ek;
    }
    ctxT[((b*4 + h)*32 + e)*32 + d] = f2bf(S / Z);
}

// ---- pass2: Q GEMM (swapped) -> exp/den -> hid^T -> Wout GEMM -> rmsnorm -> store ----
template<int MODE>
__global__ __launch_bounds__(256, 4) void la_pass2(
    const float* __restrict__ x, const float* __restrict__ g_in,
    const short* __restrict__ wq, const short* __restrict__ xnfrag,
    const short* __restrict__ ctxT, const short* __restrict__ wout,
    const float* __restrict__ b_out, const float* __restrict__ g_out,
    float* __restrict__ out)
{
    extern __shared__ char dynz[];
    const int tid = threadIdx.x, lane = tid & 63, wid = tid >> 6;
    const int g = (lane >> 4) & 3, m = lane & 15;
    const int blk = blockIdx.x;
    const int batch = blk / 864, cb = blk % 864;
    const int cq = cb * 4 + wid;              // 32-pos chunk index within batch
    const int posbase = cq * 32;

    bf16x8 af[2][2];
    if constexpr (MODE == 0) {
        const int slot = batch * 3456 + cq;
#pragma unroll
        for (int f = 0; f < 4; ++f)
            af[f >> 1][f & 1] = *(const bf16x8*)(xnfrag + ((size_t)(slot * 4 + f) * 64 + lane) * 8);
    } else {
        const int p = lane & 31, chb = (lane >> 5) * 32;
        const float* xb = x + ((size_t)batch * 64 + chb) * NPOS + posbase + p;
        float xv[32]; float ss = 0.f;
#pragma unroll
        for (int c = 0; c < 32; ++c) { float t = xb[(size_t)c * NPOS]; xv[c] = t; ss += t * t; }
        ss += __shfl_xor(ss, 32);
        float rn = 8.0f / fmaxf(sqrtf(ss), 1e-12f);
#pragma unroll
        for (int c = 0; c < 32; ++c) xv[c] *= rn * g_in[chb + c];
        char* zn = dynz + wid * 4096;
#pragma unroll
        for (int qq = 0; qq < 4; ++qq) {
            u32x4 w;
            w.x = pack2(xv[qq*8+0], xv[qq*8+1]);
            w.y = pack2(xv[qq*8+2], xv[qq*8+3]);
            w.z = pack2(xv[qq*8+4], xv[qq*8+5]);
            w.w = pack2(xv[qq*8+6], xv[qq*8+7]);
            int chunk = (lane >> 5) * 4 + qq;
            *(u32x4*)(zn + p * 128 + ((chunk ^ (p & 7)) << 4)) = w;
        }
        asm volatile("s_waitcnt lgkmcnt(0)" ::: "memory");
#pragma unroll
        for (int f = 0; f < 4; ++f) {
            int mt = f >> 1, kf = f & 1, row = mt * 16 + m;
            af[mt][kf] = *(const bf16x8*)(zn + row * 128 + (((kf*4+g) ^ (row & 7)) << 4));
        }
    }

    f32x4 oacc[4][2];
#pragma unroll
    for (int cm = 0; cm < 4; ++cm)
#pragma unroll
        for (int pt = 0; pt < 2; ++pt) oacc[cm][pt] = (f32x4){0.f, 0.f, 0.f, 0.f};

    const float scale = 0.17677669529663687f;   // 32^-0.5

#pragma unroll 1
    for (int h = 0; h < 4; ++h) {
        // EQ^T = mfma(Wq, Xn^T): rows d, cols p
        u32 eqpk[2][2][2];
        float dpart[2] = {0.f, 0.f};
#pragma unroll
        for (int dt = 0; dt < 2; ++dt) {
            const short* wr = wq + (size_t)(h*32 + dt*16 + m) * 64 + g * 8;
            bf16x8 w0 = *(const bf16x8*)wr;
            bf16x8 w1 = *(const bf16x8*)(wr + 32);
#pragma unroll
            for (int pt = 0; pt < 2; ++pt) {
                f32x4 a = {0.f, 0.f, 0.f, 0.f};
                a = MFMA(w0, af[pt][0], a, 0, 0, 0);
                a = MFMA(w1, af[pt][1], a, 0, 0, 0);
                float e0 = __expf(a[0]), e1 = __expf(a[1]);
                float e2 = __expf(a[2]), e3 = __expf(a[3]);
                dpart[pt] += (e0 + e1) + (e2 + e3);
                eqpk[dt][pt][0] = pack2(e0, e1);
                eqpk[dt][pt][1] = pack2(e2, e3);
            }
        }
        float inv[2];
#pragma unroll
        for (int pt = 0; pt < 2; ++pt) {
            float dn = dpart[pt];
            dn += __shfl_xor(dn, 16);
            dn += __shfl_xor(dn, 32);
            inv[pt] = scale / dn;
        }
        // hid^T = mfma(ctx^T, EQ^T): rows e, cols p
        bf16x8 cfr[2];
#pragma unroll
        for (int E = 0; E < 2; ++E)
            cfr[E] = *(const bf16x8*)(ctxT + (size_t)((batch*4 + h)*32 + E*16 + m) * 32 + g * 8);
        u32 hpk[2][2][2];
#pragma unroll
        for (int pt = 0; pt < 2; ++pt) {
            bf16x8 bfr = xpose(eqpk[0][pt], eqpk[1][pt], g, m);
#pragma unroll
            for (int E = 0; E < 2; ++E) {
                f32x4 hh = {0.f, 0.f, 0.f, 0.f};
                hh = MFMA(cfr[E], bfr, hh, 0, 0, 0);
                hpk[E][pt][0] = pack2(hh[0] * inv[pt], hh[1] * inv[pt]);
                hpk[E][pt][1] = pack2(hh[2] * inv[pt], hh[3] * inv[pt]);
            }
        }
        // out^T += mfma(Wout, hid^T): rows c, cols p
#pragma unroll
        for (int pt = 0; pt < 2; ++pt) {
            bf16x8 hb = xpose(hpk[0][pt], hpk[1][pt], g, m);
#pragma unroll
            for (int cm = 0; cm < 4; ++cm) {
                bf16x8 wf = *(const bf16x8*)(wout + (size_t)(cm*16 + m) * 128 + h*32 + g*8);
                oacc[cm][pt] = MFMA(wf, hb, oacc[cm][pt], 0, 0, 0);
            }
        }
    }

    // epilogue: +b_out, rmsnorm over c, *g_out, store
    float bo[4][4], go[4][4];
#pragma unroll
    for (int cm = 0; cm < 4; ++cm)
#pragma unroll
        for (int r = 0; r < 4; ++r) {
            int c = cm*16 + g*4 + r;
            bo[cm][r] = b_out[c];
            go[cm][r] = g_out[c];
        }
    float* ob = out + (size_t)batch * 64 * NPOS;
#pragma unroll
    for (int pt = 0; pt < 2; ++pt) {
        float vv[4][4]; float s2 = 0.f;
#pragma unroll
        for (int cm = 0; cm < 4; ++cm)
#pragma unroll
            for (int r = 0; r < 4; ++r) {
                float v = oacc[cm][pt][r] + bo[cm][r];
                vv[cm][r] = v;
                s2 += v * v;
            }
        s2 += __shfl_xor(s2, 16);
        s2 += __shfl_xor(s2, 32);
        float rn2 = 8.0f / fmaxf(sqrtf(s2), 1e-12f);
        int pn = posbase + pt*16 + m;
#pragma unroll
        for (int cm = 0; cm < 4; ++cm)
#pragma unroll
            for (int r = 0; r < 4; ++r)
                ob[(size_t)(cm*16 + g*4 + r) * NPOS + pn] = vv[cm][r] * rn2 * go[cm][r];
    }
}

extern "C" void kernel_launch(void* const* d_in, const int* in_sizes, int n_in,
                              void* d_out, int out_size, void* d_ws, size_t ws_size,
                              hipStream_t stream) {
    const float* x      = (const float*)d_in[0];
    const float* g_in   = (const float*)d_in[1];
    const float* w_qkv  = (const float*)d_in[2];
    const float* mem_kv = (const float*)d_in[3];
    const float* w_out  = (const float*)d_in[4];
    const float* b_out  = (const float*)d_in[5];
    const float* g_out  = (const float*)d_in[6];
    float* out = (float*)d_out;

    char* ws = (char*)d_ws;
    short* wqkv_bf = (short*)(ws);                       // 24576 bf16
    short* wout_bf = (short*)(ws + 49152);               // 8192 bf16
    float* ctxG    = (float*)(ws + 65536);               // 2*4096 f32
    float* zG      = (float*)(ws + 98304);               // 2*128 f32
    short* ctxT    = (short*)(ws + 99328);               // 8192 bf16
    float* partials = (float*)(ws + 131072);             // 864*4224 f32 = 14598144 B
    short* xnfrag  = (short*)(ws + 131072 + 14598144);   // 14155776 bf16 = 28311552 B

    const size_t need = 131072ULL + 14598144ULL + 28311552ULL;
    const bool fancy = ws_size >= need;

    la_prep<<<96, 256, 0, stream>>>(w_qkv, w_out, wqkv_bf, wout_bf);
    if (fancy) {
        la_pass1<0><<<864, 256, 0, stream>>>(x, g_in, wqkv_bf, xnfrag, partials, ctxG, zG);
        la_reduce<<<33, 256, 0, stream>>>(partials, ctxG, zG);
        la_ctxt<<<32, 256, 0, stream>>>(ctxG, zG, mem_kv, ctxT);
        la_pass2<0><<<1728, 256, 0, stream>>>(x, g_in, wqkv_bf, xnfrag, ctxT, wout_bf,
                                              b_out, g_out, out);
    } else {
        hipMemsetAsync(ws + 65536, 0, 33792, stream);
        la_pass1<1><<<864, 256, 0, stream>>>(x, g_in, wqkv_bf, xnfrag, partials, ctxG, zG);
        la_ctxt<<<32, 256, 0, stream>>>(ctxG, zG, mem_kv, ctxT);
        la_pass2<1><<<1728, 256, 16384, stream>>>(x, g_in, wqkv_bf, xnfrag, ctxT, wout_bf,
                                                  b_out, g_out, out);
    }
}

// Round 4
// 189.296 us; speedup vs baseline: 1.4555x; 1.4555x over previous
//
#include <hip/hip_runtime.h>
#include <math.h>

#define NPOS 110592

typedef float f32x4 __attribute__((ext_vector_type(4)));
typedef short bf16x8 __attribute__((ext_vector_type(8)));
typedef unsigned u32;

#define MFMA __builtin_amdgcn_mfma_f32_16x16x32_bf16

__device__ __forceinline__ short f2bf(float f) {
    u32 u = __builtin_bit_cast(u32, f);
    u += 0x7fffu + ((u >> 16) & 1u);
    return (short)(u >> 16);
}
__device__ __forceinline__ u32 pack2(float a, float b) {
    return (u32)(unsigned short)f2bf(a) | ((u32)(unsigned short)f2bf(b) << 16);
}

union FragU { u32 w[4]; bf16x8 v; };

// In-register transpose: two C-layout tiles (rows = future K, 16 each) -> one
// A/B fragment for a K=32 MFMA. pk*[2] = {pack2(acc0,acc1), pack2(acc2,acc3)}.
// Target lane (g,m), u32 q holds k=2q,2q+1: src tile = g>>1 (register select),
// src lane = ((g&1)*2 + (q>>1))*16 + m, src u32 = q&1.   (validated round 3)
__device__ __forceinline__ bf16x8 xpose(const u32* pk0, const u32* pk1, int g, int m) {
    int s0 = ((((g & 1) * 2 + 0) * 16 + m) << 2);
    int s1 = ((((g & 1) * 2 + 1) * 16 + m) << 2);
    u32 a0 = (u32)__builtin_amdgcn_ds_bpermute(s0, (int)pk0[0]);
    u32 a1 = (u32)__builtin_amdgcn_ds_bpermute(s0, (int)pk0[1]);
    u32 a2 = (u32)__builtin_amdgcn_ds_bpermute(s1, (int)pk0[0]);
    u32 a3 = (u32)__builtin_amdgcn_ds_bpermute(s1, (int)pk0[1]);
    u32 b0 = (u32)__builtin_amdgcn_ds_bpermute(s0, (int)pk1[0]);
    u32 b1 = (u32)__builtin_amdgcn_ds_bpermute(s0, (int)pk1[1]);
    u32 b2 = (u32)__builtin_amdgcn_ds_bpermute(s1, (int)pk1[0]);
    u32 b3 = (u32)__builtin_amdgcn_ds_bpermute(s1, (int)pk1[1]);
    bool hi = g >= 2;
    FragU f;
    f.w[0] = hi ? b0 : a0;
    f.w[1] = hi ? b1 : a1;
    f.w[2] = hi ? b2 : a2;
    f.w[3] = hi ? b3 : a3;
    return f.v;
}

// Direct global -> A-fragment load with fused rmsnorm (g_in pre-folded into weights).
// lane(g,m): af[mt][kf] holds xn[pos = posbase+mt*16+m][c = kf*32+g*8+j]*rn.
__device__ __forceinline__ void load_xn_frags(const float* __restrict__ xb,
                                              int posbase, int g, int m,
                                              bf16x8 af[2][2])
{
#pragma unroll
    for (int mt = 0; mt < 2; ++mt) {
        const float* base = xb + posbase + mt * 16 + m;
        float xv[16]; float ss = 0.f;
#pragma unroll
        for (int kf = 0; kf < 2; ++kf)
#pragma unroll
            for (int j = 0; j < 8; ++j) {
                float t = base[(size_t)(kf * 32 + g * 8 + j) * NPOS];
                xv[kf * 8 + j] = t; ss += t * t;
            }
        ss += __shfl_xor(ss, 16);
        ss += __shfl_xor(ss, 32);
        float rn = 8.0f / fmaxf(sqrtf(ss), 1e-12f);
#pragma unroll
        for (int kf = 0; kf < 2; ++kf) {
            FragU f;
            f.w[0] = pack2(xv[kf*8+0] * rn, xv[kf*8+1] * rn);
            f.w[1] = pack2(xv[kf*8+2] * rn, xv[kf*8+3] * rn);
            f.w[2] = pack2(xv[kf*8+4] * rn, xv[kf*8+5] * rn);
            f.w[3] = pack2(xv[kf*8+6] * rn, xv[kf*8+7] * rn);
            af[mt][kf] = f.v;
        }
    }
}

// ---- prep: bf16 weights, g_in folded into w_qkv columns ----
__global__ __launch_bounds__(256) void la_prep(const float* __restrict__ wqkv,
                                               const float* __restrict__ g_in,
                                               const float* __restrict__ wout,
                                               short* __restrict__ wqkv_bf,
                                               short* __restrict__ wout_bf)
{
    int i = blockIdx.x * 256 + threadIdx.x;
    if (i < 24576) wqkv_bf[i] = f2bf(wqkv[i] * g_in[i & 63]);
    if (i < 8192)  wout_bf[i] = f2bf(wout[i]);
}

// ---- pass1: wave-autonomous. wave = 32 positions x 2 heads. No LDS, no barriers.
// K,V GEMM -> exp -> in-reg xpose -> ctx accumulated in MFMA acc regs -> one flush.
__global__ __launch_bounds__(256, 4) void la_pass1(
    const float* __restrict__ x, const short* __restrict__ wkv,
    float* __restrict__ ctxG2)
{
    const int tid = threadIdx.x, lane = tid & 63, wid = tid >> 6;
    const int g = lane >> 4, m = lane & 15;
    const int blk = blockIdx.x;
    const int batch = blk / 1728, cp = blk % 1728;
    const int chunk = cp * 2 + (wid & 1);      // [0, 3456)
    const int hbase = (wid >> 1) * 2;          // heads {0,1} or {2,3}
    const int posbase = chunk * 32;

    bf16x8 af[2][2];
    load_xn_frags(x + (size_t)batch * 64 * NPOS, posbase, g, m, af);

    f32x4 acc[2][2][2];
#pragma unroll
    for (int hh = 0; hh < 2; ++hh)
#pragma unroll
        for (int D = 0; D < 2; ++D)
#pragma unroll
            for (int E = 0; E < 2; ++E) acc[hh][D][E] = (f32x4){0.f, 0.f, 0.f, 0.f};
    float zacc[2][2] = {{0.f, 0.f}, {0.f, 0.f}};

#pragma unroll
    for (int hh = 0; hh < 2; ++hh) {
        const int h = hbase + hh;
        u32 ekpk[2][2][2], vpk[2][2][2];
#pragma unroll
        for (int nt2 = 0; nt2 < 2; ++nt2) {
            const short* wr = wkv + (size_t)(128 + h * 32 + nt2 * 16 + m) * 64 + g * 8;
            bf16x8 w0 = *(const bf16x8*)wr;
            bf16x8 w1 = *(const bf16x8*)(wr + 32);
#pragma unroll
            for (int mt = 0; mt < 2; ++mt) {
                f32x4 a = {0.f, 0.f, 0.f, 0.f};
                a = MFMA(af[mt][0], w0, a, 0, 0, 0);
                a = MFMA(af[mt][1], w1, a, 0, 0, 0);
                float e0 = __expf(a[0]), e1 = __expf(a[1]);
                float e2 = __expf(a[2]), e3 = __expf(a[3]);
                zacc[hh][nt2] += (e0 + e1) + (e2 + e3);
                ekpk[nt2][mt][0] = pack2(e0, e1);
                ekpk[nt2][mt][1] = pack2(e2, e3);
            }
        }
#pragma unroll
        for (int nt2 = 0; nt2 < 2; ++nt2) {
            const short* wr = wkv + (size_t)(256 + h * 32 + nt2 * 16 + m) * 64 + g * 8;
            bf16x8 w0 = *(const bf16x8*)wr;
            bf16x8 w1 = *(const bf16x8*)(wr + 32);
#pragma unroll
            for (int mt = 0; mt < 2; ++mt) {
                f32x4 a = {0.f, 0.f, 0.f, 0.f};
                a = MFMA(af[mt][0], w0, a, 0, 0, 0);
                a = MFMA(af[mt][1], w1, a, 0, 0, 0);
                vpk[nt2][mt][0] = pack2(a[0], a[1]);
                vpk[nt2][mt][1] = pack2(a[2], a[3]);
            }
        }
        bf16x8 afr[2], bfr[2];
#pragma unroll
        for (int t2 = 0; t2 < 2; ++t2) {
            afr[t2] = xpose(ekpk[t2][0], ekpk[t2][1], g, m);
            bfr[t2] = xpose(vpk[t2][0], vpk[t2][1], g, m);
        }
#pragma unroll
        for (int D = 0; D < 2; ++D)
#pragma unroll
            for (int E = 0; E < 2; ++E)
                acc[hh][D][E] = MFMA(afr[D], bfr[E], acc[hh][D][E], 0, 0, 0);
    }

    // one flush per wave, into 64 contention-spreading slots
    const int slot = (blk * 4 + wid) & 63;
    float* cs = ctxG2 + ((size_t)batch * 64 + slot) * 4224;
#pragma unroll
    for (int hh = 0; hh < 2; ++hh) {
#pragma unroll
        for (int D = 0; D < 2; ++D)
#pragma unroll
            for (int E = 0; E < 2; ++E)
#pragma unroll
                for (int r = 0; r < 4; ++r)
                    atomicAdd(&cs[(hbase + hh) * 1024 + (D * 16 + g * 4 + r) * 32 + E * 16 + m],
                              acc[hh][D][E][r]);
#pragma unroll
        for (int nt2 = 0; nt2 < 2; ++nt2) {
            float z = zacc[hh][nt2];
            z += __shfl_xor(z, 16);
            z += __shfl_xor(z, 32);
            if (g == 0) atomicAdd(&cs[4096 + (hbase + hh) * 32 + nt2 * 16 + m], z);
        }
    }
}

// ---- reduce 64 slots + fold mem_kv + normalize -> ctxT[b][h][e][d] bf16 ----
__global__ __launch_bounds__(256) void la_ctxt(const float* __restrict__ ctxG2,
                                               const float* __restrict__ mem_kv,
                                               short* __restrict__ ctxT)
{
    int t = blockIdx.x * 256 + threadIdx.x;
    if (t >= 8192) return;
    int b = t >> 12, r = t & 4095, h = r >> 10, de = r & 1023, d = de >> 5, e = de & 31;
    const float* base = ctxG2 + (size_t)b * 64 * 4224;
    float S = 0.f, Z = 0.f;
    for (int s = 0; s < 64; ++s) {
        S += base[s * 4224 + h * 1024 + d * 32 + e];
        Z += base[s * 4224 + 4096 + h * 32 + d];
    }
    const float* mk = mem_kv + (h * 32 + d) * 4;
    const float* mv = mem_kv + 512 + (h * 32 + e) * 4;
#pragma unroll
    for (int mm = 0; mm < 4; ++mm) {
        float ek = __expf(mk[mm]);
        S += ek * mv[mm];
        Z += ek;
    }
    ctxT[((b * 4 + h) * 32 + e) * 32 + d] = f2bf(S / Z);
}

// ---- pass2: wave-autonomous 32-pos chunk, all 4 heads. No LDS, no barriers. ----
__global__ __launch_bounds__(256, 4) void la_pass2(
    const float* __restrict__ x, const short* __restrict__ wq,
    const short* __restrict__ ctxT, const short* __restrict__ wout,
    const float* __restrict__ b_out, const float* __restrict__ g_out,
    float* __restrict__ out)
{
    const int tid = threadIdx.x, lane = tid & 63, wid = tid >> 6;
    const int g = lane >> 4, m = lane & 15;
    const int blk = blockIdx.x;
    const int batch = blk / 864;
    const int cq = (blk % 864) * 4 + wid;      // [0, 3456)
    const int posbase = cq * 32;

    bf16x8 af[2][2];
    load_xn_frags(x + (size_t)batch * 64 * NPOS, posbase, g, m, af);

    f32x4 oacc[4][2];
#pragma unroll
    for (int cm = 0; cm < 4; ++cm)
#pragma unroll
        for (int pt = 0; pt < 2; ++pt) oacc[cm][pt] = (f32x4){0.f, 0.f, 0.f, 0.f};

    const float scale = 0.17677669529663687f;   // 32^-0.5

#pragma unroll 1
    for (int h = 0; h < 4; ++h) {
        // EQ^T = mfma(Wq, Xn^T): rows d, cols p
        u32 eqpk[2][2][2];
        float dpart[2] = {0.f, 0.f};
#pragma unroll
        for (int dt = 0; dt < 2; ++dt) {
            const short* wr = wq + (size_t)(h * 32 + dt * 16 + m) * 64 + g * 8;
            bf16x8 w0 = *(const bf16x8*)wr;
            bf16x8 w1 = *(const bf16x8*)(wr + 32);
#pragma unroll
            for (int pt = 0; pt < 2; ++pt) {
                f32x4 a = {0.f, 0.f, 0.f, 0.f};
                a = MFMA(w0, af[pt][0], a, 0, 0, 0);
                a = MFMA(w1, af[pt][1], a, 0, 0, 0);
                float e0 = __expf(a[0]), e1 = __expf(a[1]);
                float e2 = __expf(a[2]), e3 = __expf(a[3]);
                dpart[pt] += (e0 + e1) + (e2 + e3);
                eqpk[dt][pt][0] = pack2(e0, e1);
                eqpk[dt][pt][1] = pack2(e2, e3);
            }
        }
        float inv[2];
#pragma unroll
        for (int pt = 0; pt < 2; ++pt) {
            float dn = dpart[pt];
            dn += __shfl_xor(dn, 16);
            dn += __shfl_xor(dn, 32);
            inv[pt] = scale / dn;
        }
        // hid^T = mfma(ctx^T, EQ^T): rows e, cols p
        bf16x8 cfr[2];
#pragma unroll
        for (int E = 0; E < 2; ++E)
            cfr[E] = *(const bf16x8*)(ctxT + (size_t)((batch * 4 + h) * 32 + E * 16 + m) * 32 + g * 8);
        u32 hpk[2][2][2];
#pragma unroll
        for (int pt = 0; pt < 2; ++pt) {
            bf16x8 bfr = xpose(eqpk[0][pt], eqpk[1][pt], g, m);
#pragma unroll
            for (int E = 0; E < 2; ++E) {
                f32x4 hh = {0.f, 0.f, 0.f, 0.f};
                hh = MFMA(cfr[E], bfr, hh, 0, 0, 0);
                hpk[E][pt][0] = pack2(hh[0] * inv[pt], hh[1] * inv[pt]);
                hpk[E][pt][1] = pack2(hh[2] * inv[pt], hh[3] * inv[pt]);
            }
        }
        // out^T += mfma(Wout, hid^T): rows c, cols p
#pragma unroll
        for (int pt = 0; pt < 2; ++pt) {
            bf16x8 hb = xpose(hpk[0][pt], hpk[1][pt], g, m);
#pragma unroll
            for (int cm = 0; cm < 4; ++cm) {
                bf16x8 wf = *(const bf16x8*)(wout + (size_t)(cm * 16 + m) * 128 + h * 32 + g * 8);
                oacc[cm][pt] = MFMA(wf, hb, oacc[cm][pt], 0, 0, 0);
            }
        }
    }

    // epilogue: +b_out, rmsnorm over c, *g_out, store
    float bo[4][4], go[4][4];
#pragma unroll
    for (int cm = 0; cm < 4; ++cm)
#pragma unroll
        for (int r = 0; r < 4; ++r) {
            int c = cm * 16 + g * 4 + r;
            bo[cm][r] = b_out[c];
            go[cm][r] = g_out[c];
        }
    float* ob = out + (size_t)batch * 64 * NPOS;
#pragma unroll
    for (int pt = 0; pt < 2; ++pt) {
        float vv[4][4]; float s2 = 0.f;
#pragma unroll
        for (int cm = 0; cm < 4; ++cm)
#pragma unroll
            for (int r = 0; r < 4; ++r) {
                float v = oacc[cm][pt][r] + bo[cm][r];
                vv[cm][r] = v;
                s2 += v * v;
            }
        s2 += __shfl_xor(s2, 16);
        s2 += __shfl_xor(s2, 32);
        float rn2 = 8.0f / fmaxf(sqrtf(s2), 1e-12f);
        int pn = posbase + pt * 16 + m;
#pragma unroll
        for (int cm = 0; cm < 4; ++cm)
#pragma unroll
            for (int r = 0; r < 4; ++r)
                ob[(size_t)(cm * 16 + g * 4 + r) * NPOS + pn] = vv[cm][r] * rn2 * go[cm][r];
    }
}

extern "C" void kernel_launch(void* const* d_in, const int* in_sizes, int n_in,
                              void* d_out, int out_size, void* d_ws, size_t ws_size,
                              hipStream_t stream) {
    const float* x      = (const float*)d_in[0];
    const float* g_in   = (const float*)d_in[1];
    const float* w_qkv  = (const float*)d_in[2];
    const float* mem_kv = (const float*)d_in[3];
    const float* w_out  = (const float*)d_in[4];
    const float* b_out  = (const float*)d_in[5];
    const float* g_out  = (const float*)d_in[6];
    float* out = (float*)d_out;

    char* ws = (char*)d_ws;
    short* wqkv_bf = (short*)(ws);             // 24576 bf16 = 49152 B
    short* wout_bf = (short*)(ws + 49152);     // 8192 bf16  = 16384 B
    short* ctxT    = (short*)(ws + 65536);     // 8192 bf16  = 16384 B
    float* ctxG2   = (float*)(ws + 81920);     // 2*64*4224 f32 = 2162688 B

    hipMemsetAsync(ctxG2, 0, 2ULL * 64 * 4224 * 4, stream);
    la_prep<<<96, 256, 0, stream>>>(w_qkv, g_in, w_out, wqkv_bf, wout_bf);
    la_pass1<<<3456, 256, 0, stream>>>(x, wqkv_bf, ctxG2);
    la_ctxt<<<32, 256, 0, stream>>>(ctxG2, mem_kv, ctxT);
    la_pass2<<<1728, 256, 0, stream>>>(x, wqkv_bf, ctxT, wout_bf, b_out, g_out, out);
}

// Round 5
// 165.582 us; speedup vs baseline: 1.6639x; 1.1432x over previous
//
#include <hip/hip_runtime.h>
#include <math.h>

#define NPOS 110592

typedef float f32x4 __attribute__((ext_vector_type(4)));
typedef short bf16x8 __attribute__((ext_vector_type(8)));
typedef unsigned u32;
typedef u32 u32x4 __attribute__((ext_vector_type(4)));

#define MFMA __builtin_amdgcn_mfma_f32_16x16x32_bf16

__device__ __forceinline__ short f2bf(float f) {
    u32 u = __builtin_bit_cast(u32, f);
    u += 0x7fffu + ((u >> 16) & 1u);
    return (short)(u >> 16);
}
__device__ __forceinline__ u32 pack2(float a, float b) {
    return (u32)(unsigned short)f2bf(a) | ((u32)(unsigned short)f2bf(b) << 16);
}

union FragU { u32 w[4]; bf16x8 v; };

// In-register transpose: two C-layout tiles (rows = future K, 16 each) -> one
// A/B fragment for a K=32 MFMA. pk*[2] = {pack2(acc0,acc1), pack2(acc2,acc3)}.
// Target lane (g,m), u32 q holds k=2q,2q+1: src tile = g>>1 (register select),
// src lane = ((g&1)*2 + (q>>1))*16 + m, src u32 = q&1.   (validated rounds 3-4)
__device__ __forceinline__ bf16x8 xpose(const u32* pk0, const u32* pk1, int g, int m) {
    int s0 = ((((g & 1) * 2 + 0) * 16 + m) << 2);
    int s1 = ((((g & 1) * 2 + 1) * 16 + m) << 2);
    u32 a0 = (u32)__builtin_amdgcn_ds_bpermute(s0, (int)pk0[0]);
    u32 a1 = (u32)__builtin_amdgcn_ds_bpermute(s0, (int)pk0[1]);
    u32 a2 = (u32)__builtin_amdgcn_ds_bpermute(s1, (int)pk0[0]);
    u32 a3 = (u32)__builtin_amdgcn_ds_bpermute(s1, (int)pk0[1]);
    u32 b0 = (u32)__builtin_amdgcn_ds_bpermute(s0, (int)pk1[0]);
    u32 b1 = (u32)__builtin_amdgcn_ds_bpermute(s0, (int)pk1[1]);
    u32 b2 = (u32)__builtin_amdgcn_ds_bpermute(s1, (int)pk1[0]);
    u32 b3 = (u32)__builtin_amdgcn_ds_bpermute(s1, (int)pk1[1]);
    bool hi = g >= 2;
    FragU f;
    f.w[0] = hi ? b0 : a0;
    f.w[1] = hi ? b1 : a1;
    f.w[2] = hi ? b2 : a2;
    f.w[3] = hi ? b3 : a3;
    return f.v;
}

// ---- prep: bf16 weights, g_in folded into w_qkv columns ----
__global__ __launch_bounds__(256) void la_prep(const float* __restrict__ wqkv,
                                               const float* __restrict__ g_in,
                                               const float* __restrict__ wout,
                                               short* __restrict__ wqkv_bf,
                                               short* __restrict__ wout_bf)
{
    int i = blockIdx.x * 256 + threadIdx.x;
    if (i < 24576) wqkv_bf[i] = f2bf(wqkv[i] * g_in[i & 63]);
    if (i < 8192)  wout_bf[i] = f2bf(wout[i]);
}

// ---- pass0: coalesced x read, in-thread rmsnorm, write bf16 xnT[pos][64] via LDS stage ----
__global__ __launch_bounds__(256, 4) void la_pass0(
    const float* __restrict__ x, short* __restrict__ xnT)
{
    __shared__ __align__(16) char lds[32768];
    const int tid = threadIdx.x;
    const int blk = blockIdx.x;
    const int batch = blk / 432;
    const int pb = (blk % 432) * 256;

    const float* base = x + (size_t)batch * 64 * NPOS + pb + tid;
    float xv[64]; float ss = 0.f;
#pragma unroll
    for (int c = 0; c < 64; ++c) { float t = base[(size_t)c * NPOS]; xv[c] = t; ss += t * t; }
    float rn = 8.0f / fmaxf(sqrtf(ss), 1e-12f);

    char* row = lds + tid * 128;
#pragma unroll
    for (int ch = 0; ch < 8; ++ch) {
        u32x4 w;
        w.x = pack2(xv[ch*8+0] * rn, xv[ch*8+1] * rn);
        w.y = pack2(xv[ch*8+2] * rn, xv[ch*8+3] * rn);
        w.z = pack2(xv[ch*8+4] * rn, xv[ch*8+5] * rn);
        w.w = pack2(xv[ch*8+6] * rn, xv[ch*8+7] * rn);
        *(u32x4*)(row + ((ch ^ (tid & 7)) << 4)) = w;
    }
    __syncthreads();
    char* dst = (char*)xnT + ((size_t)batch * NPOS + pb) * 128;
#pragma unroll
    for (int i = 0; i < 8; ++i) {
        int u = i * 256 + tid;
        int r = u >> 3, cl = u & 7;
        u32x4 w = *(const u32x4*)(lds + r * 128 + ((cl ^ (r & 7)) << 4));
        *(u32x4*)(dst + (size_t)u * 16) = w;
    }
}

// ---- pass1: wave = 4 chunks x 2 heads, acc in regs, LDS combine, partial store. No atomics. ----
__global__ __launch_bounds__(256, 4) void la_pass1(
    const short* __restrict__ xnT, const short* __restrict__ wkv,
    float* __restrict__ partials)
{
    __shared__ float lctx[4][2][32][33];
    __shared__ float lz[4][2][32];
    const int tid = threadIdx.x, lane = tid & 63, wid = tid >> 6;
    const int g = lane >> 4, m = lane & 15;
    const int blk = blockIdx.x;
    const int batch = blk / 432;
    const int CB = (blk % 432) * 8 + (wid >> 1) * 4;   // this wave: chunks CB..CB+3
    const int hbase = (wid & 1) * 2;                   // heads {0,1} or {2,3}
    const short* xb = xnT + (size_t)batch * NPOS * 64;

    f32x4 acc[2][2][2];
#pragma unroll
    for (int hh = 0; hh < 2; ++hh)
#pragma unroll
        for (int D = 0; D < 2; ++D)
#pragma unroll
            for (int E = 0; E < 2; ++E) acc[hh][D][E] = (f32x4){0.f, 0.f, 0.f, 0.f};
    float zacc[2][2] = {{0.f, 0.f}, {0.f, 0.f}};

    bf16x8 af[2][2], afn[2][2];
    {
        const short* p = xb + (size_t)CB * 32 * 64;
#pragma unroll
        for (int mt = 0; mt < 2; ++mt)
#pragma unroll
            for (int kf = 0; kf < 2; ++kf)
                af[mt][kf] = *(const bf16x8*)(p + (mt * 16 + m) * 64 + kf * 32 + g * 8);
    }

#pragma unroll 1
    for (int c = 0; c < 4; ++c) {
        if (c < 3) {
            const short* p = xb + (size_t)(CB + c + 1) * 32 * 64;
#pragma unroll
            for (int mt = 0; mt < 2; ++mt)
#pragma unroll
                for (int kf = 0; kf < 2; ++kf)
                    afn[mt][kf] = *(const bf16x8*)(p + (mt * 16 + m) * 64 + kf * 32 + g * 8);
        }
#pragma unroll
        for (int hh = 0; hh < 2; ++hh) {
            const int h = hbase + hh;
            u32 ekpk[2][2][2], vpk[2][2][2];
#pragma unroll
            for (int nt2 = 0; nt2 < 2; ++nt2) {
                const short* wr = wkv + (size_t)(128 + h * 32 + nt2 * 16 + m) * 64 + g * 8;
                bf16x8 w0 = *(const bf16x8*)wr;
                bf16x8 w1 = *(const bf16x8*)(wr + 32);
#pragma unroll
                for (int mt = 0; mt < 2; ++mt) {
                    f32x4 a = {0.f, 0.f, 0.f, 0.f};
                    a = MFMA(af[mt][0], w0, a, 0, 0, 0);
                    a = MFMA(af[mt][1], w1, a, 0, 0, 0);
                    float e0 = __expf(a[0]), e1 = __expf(a[1]);
                    float e2 = __expf(a[2]), e3 = __expf(a[3]);
                    zacc[hh][nt2] += (e0 + e1) + (e2 + e3);
                    ekpk[nt2][mt][0] = pack2(e0, e1);
                    ekpk[nt2][mt][1] = pack2(e2, e3);
                }
            }
#pragma unroll
            for (int nt2 = 0; nt2 < 2; ++nt2) {
                const short* wr = wkv + (size_t)(256 + h * 32 + nt2 * 16 + m) * 64 + g * 8;
                bf16x8 w0 = *(const bf16x8*)wr;
                bf16x8 w1 = *(const bf16x8*)(wr + 32);
#pragma unroll
                for (int mt = 0; mt < 2; ++mt) {
                    f32x4 a = {0.f, 0.f, 0.f, 0.f};
                    a = MFMA(af[mt][0], w0, a, 0, 0, 0);
                    a = MFMA(af[mt][1], w1, a, 0, 0, 0);
                    vpk[nt2][mt][0] = pack2(a[0], a[1]);
                    vpk[nt2][mt][1] = pack2(a[2], a[3]);
                }
            }
            bf16x8 afr[2], bfr[2];
#pragma unroll
            for (int t2 = 0; t2 < 2; ++t2) {
                afr[t2] = xpose(ekpk[t2][0], ekpk[t2][1], g, m);
                bfr[t2] = xpose(vpk[t2][0], vpk[t2][1], g, m);
            }
#pragma unroll
            for (int D = 0; D < 2; ++D)
#pragma unroll
                for (int E = 0; E < 2; ++E)
                    acc[hh][D][E] = MFMA(afr[D], bfr[E], acc[hh][D][E], 0, 0, 0);
        }
        if (c < 3) {
#pragma unroll
            for (int mt = 0; mt < 2; ++mt)
#pragma unroll
                for (int kf = 0; kf < 2; ++kf) af[mt][kf] = afn[mt][kf];
        }
    }

    // per-wave partial -> LDS (padded stride 33 -> conflict-light), combine, store
#pragma unroll
    for (int hh = 0; hh < 2; ++hh) {
#pragma unroll
        for (int D = 0; D < 2; ++D)
#pragma unroll
            for (int E = 0; E < 2; ++E)
#pragma unroll
                for (int r = 0; r < 4; ++r)
                    lctx[wid][hh][D * 16 + g * 4 + r][E * 16 + m] = acc[hh][D][E][r];
#pragma unroll
        for (int nt2 = 0; nt2 < 2; ++nt2) {
            float z = zacc[hh][nt2];
            z += __shfl_xor(z, 16);
            z += __shfl_xor(z, 32);
            if (g == 0) lz[wid][hh][nt2 * 16 + m] = z;
        }
    }
    __syncthreads();

    float* P = partials + (size_t)blk * 4224;
    for (int i = tid; i < 4096; i += 256) {
        int h = i >> 10, de = i & 1023, d = de >> 5, e = de & 31;
        int w0 = h >> 1, hh = h & 1;
        P[i] = lctx[w0][hh][d][e] + lctx[w0 + 2][hh][d][e];
    }
    if (tid < 128) {
        int h = tid >> 5, d = tid & 31;
        P[4096 + tid] = lz[h >> 1][h & 1][d] + lz[(h >> 1) + 2][h & 1][d];
    }
}

// ---- reduce 432 block-partials per batch + fold mem_kv + normalize -> ctxT[b][h][e][d] ----
__global__ __launch_bounds__(256) void la_ctxt(const float* __restrict__ partials,
                                               const float* __restrict__ mem_kv,
                                               short* __restrict__ ctxT)
{
    int t = blockIdx.x * 256 + threadIdx.x;
    if (t >= 8192) return;
    int b = t >> 12, r = t & 4095, h = r >> 10, de = r & 1023, d = de >> 5, e = de & 31;
    const float* P = partials + (size_t)b * 432 * 4224;
    const int ci = h * 1024 + de;
    const int zi = 4096 + h * 32 + d;
    float S = 0.f, Z = 0.f;
#pragma unroll 4
    for (int j = 0; j < 432; ++j) {
        S += P[(size_t)j * 4224 + ci];
        Z += P[(size_t)j * 4224 + zi];
    }
    const float* mk = mem_kv + (h * 32 + d) * 4;
    const float* mv = mem_kv + 512 + (h * 32 + e) * 4;
#pragma unroll
    for (int mm = 0; mm < 4; ++mm) {
        float ek = __expf(mk[mm]);
        S += ek * mv[mm];
        Z += ek;
    }
    ctxT[((b * 4 + h) * 32 + e) * 32 + d] = f2bf(S / Z);
}

// ---- pass2: wave-autonomous 32-pos chunk, 4 heads (unroll 2 for ILP). No LDS/barriers. ----
__global__ __launch_bounds__(256, 4) void la_pass2(
    const short* __restrict__ xnT, const short* __restrict__ wq,
    const short* __restrict__ ctxT, const short* __restrict__ wout,
    const float* __restrict__ b_out, const float* __restrict__ g_out,
    float* __restrict__ out)
{
    const int tid = threadIdx.x, lane = tid & 63, wid = tid >> 6;
    const int g = lane >> 4, m = lane & 15;
    const int blk = blockIdx.x;
    const int batch = blk / 864;
    const int cq = (blk % 864) * 4 + wid;      // [0, 3456)
    const int posbase = cq * 32;

    const short* xp = xnT + ((size_t)batch * NPOS + posbase) * 64;
    bf16x8 af[2][2];
#pragma unroll
    for (int mt = 0; mt < 2; ++mt)
#pragma unroll
        for (int kf = 0; kf < 2; ++kf)
            af[mt][kf] = *(const bf16x8*)(xp + (mt * 16 + m) * 64 + kf * 32 + g * 8);

    f32x4 oacc[4][2];
#pragma unroll
    for (int cm = 0; cm < 4; ++cm)
#pragma unroll
        for (int pt = 0; pt < 2; ++pt) oacc[cm][pt] = (f32x4){0.f, 0.f, 0.f, 0.f};

    const float scale = 0.17677669529663687f;   // 32^-0.5

#pragma unroll 2
    for (int h = 0; h < 4; ++h) {
        // EQ^T = mfma(Wq, Xn^T): rows d, cols p
        u32 eqpk[2][2][2];
        float dpart[2] = {0.f, 0.f};
#pragma unroll
        for (int dt = 0; dt < 2; ++dt) {
            const short* wr = wq + (size_t)(h * 32 + dt * 16 + m) * 64 + g * 8;
            bf16x8 w0 = *(const bf16x8*)wr;
            bf16x8 w1 = *(const bf16x8*)(wr + 32);
#pragma unroll
            for (int pt = 0; pt < 2; ++pt) {
                f32x4 a = {0.f, 0.f, 0.f, 0.f};
                a = MFMA(w0, af[pt][0], a, 0, 0, 0);
                a = MFMA(w1, af[pt][1], a, 0, 0, 0);
                float e0 = __expf(a[0]), e1 = __expf(a[1]);
                float e2 = __expf(a[2]), e3 = __expf(a[3]);
                dpart[pt] += (e0 + e1) + (e2 + e3);
                eqpk[dt][pt][0] = pack2(e0, e1);
                eqpk[dt][pt][1] = pack2(e2, e3);
            }
        }
        float inv[2];
#pragma unroll
        for (int pt = 0; pt < 2; ++pt) {
            float dn = dpart[pt];
            dn += __shfl_xor(dn, 16);
            dn += __shfl_xor(dn, 32);
            inv[pt] = scale / dn;
        }
        // hid^T = mfma(ctx^T, EQ^T): rows e, cols p
        bf16x8 cfr[2];
#pragma unroll
        for (int E = 0; E < 2; ++E)
            cfr[E] = *(const bf16x8*)(ctxT + (size_t)((batch * 4 + h) * 32 + E * 16 + m) * 32 + g * 8);
        u32 hpk[2][2][2];
#pragma unroll
        for (int pt = 0; pt < 2; ++pt) {
            bf16x8 bfr = xpose(eqpk[0][pt], eqpk[1][pt], g, m);
#pragma unroll
            for (int E = 0; E < 2; ++E) {
                f32x4 hh = {0.f, 0.f, 0.f, 0.f};
                hh = MFMA(cfr[E], bfr, hh, 0, 0, 0);
                hpk[E][pt][0] = pack2(hh[0] * inv[pt], hh[1] * inv[pt]);
                hpk[E][pt][1] = pack2(hh[2] * inv[pt], hh[3] * inv[pt]);
            }
        }
        // out^T += mfma(Wout, hid^T): rows c, cols p
#pragma unroll
        for (int pt = 0; pt < 2; ++pt) {
            bf16x8 hb = xpose(hpk[0][pt], hpk[1][pt], g, m);
#pragma unroll
            for (int cm = 0; cm < 4; ++cm) {
                bf16x8 wf = *(const bf16x8*)(wout + (size_t)(cm * 16 + m) * 128 + h * 32 + g * 8);
                oacc[cm][pt] = MFMA(wf, hb, oacc[cm][pt], 0, 0, 0);
            }
        }
    }

    // epilogue: +b_out, rmsnorm over c, *g_out, store
    float bo[4][4], go[4][4];
#pragma unroll
    for (int cm = 0; cm < 4; ++cm)
#pragma unroll
        for (int r = 0; r < 4; ++r) {
            int c = cm * 16 + g * 4 + r;
            bo[cm][r] = b_out[c];
            go[cm][r] = g_out[c];
        }
    float* ob = out + (size_t)batch * 64 * NPOS;
#pragma unroll
    for (int pt = 0; pt < 2; ++pt) {
        float vv[4][4]; float s2 = 0.f;
#pragma unroll
        for (int cm = 0; cm < 4; ++cm)
#pragma unroll
            for (int r = 0; r < 4; ++r) {
                float v = oacc[cm][pt][r] + bo[cm][r];
                vv[cm][r] = v;
                s2 += v * v;
            }
        s2 += __shfl_xor(s2, 16);
        s2 += __shfl_xor(s2, 32);
        float rn2 = 8.0f / fmaxf(sqrtf(s2), 1e-12f);
        int pn = posbase + pt * 16 + m;
#pragma unroll
        for (int cm = 0; cm < 4; ++cm)
#pragma unroll
            for (int r = 0; r < 4; ++r)
                ob[(size_t)(cm * 16 + g * 4 + r) * NPOS + pn] = vv[cm][r] * rn2 * go[cm][r];
    }
}

extern "C" void kernel_launch(void* const* d_in, const int* in_sizes, int n_in,
                              void* d_out, int out_size, void* d_ws, size_t ws_size,
                              hipStream_t stream) {
    const float* x      = (const float*)d_in[0];
    const float* g_in   = (const float*)d_in[1];
    const float* w_qkv  = (const float*)d_in[2];
    const float* mem_kv = (const float*)d_in[3];
    const float* w_out  = (const float*)d_in[4];
    const float* b_out  = (const float*)d_in[5];
    const float* g_out  = (const float*)d_in[6];
    float* out = (float*)d_out;

    char* ws = (char*)d_ws;
    short* xnT      = (short*)(ws);                    // 2*110592*64 bf16 = 28,311,552 B
    float* partials = (float*)(ws + 28311552);         // 864*4224 f32    = 14,598,144 B
    short* wqkv_bf  = (short*)(ws + 42909696);         // 24576 bf16
    short* wout_bf  = (short*)(ws + 42958848);         // 8192 bf16
    short* ctxT     = (short*)(ws + 42975232);         // 8192 bf16; end = 42,991,616 B

    la_prep<<<96, 256, 0, stream>>>(w_qkv, g_in, w_out, wqkv_bf, wout_bf);
    la_pass0<<<864, 256, 0, stream>>>(x, xnT);
    la_pass1<<<864, 256, 0, stream>>>(xnT, wqkv_bf, partials);
    la_ctxt<<<32, 256, 0, stream>>>(partials, mem_kv, ctxT);
    la_pass2<<<1728, 256, 0, stream>>>(xnT, wqkv_bf, ctxT, wout_bf, b_out, g_out, out);
}

// Round 6
// 145.550 us; speedup vs baseline: 1.8929x; 1.1376x over previous
//
#include <hip/hip_runtime.h>
#include <math.h>

#define NPOS 110592

typedef float f32x4 __attribute__((ext_vector_type(4)));
typedef short bf16x8 __attribute__((ext_vector_type(8)));
typedef unsigned u32;
typedef u32 u32x2 __attribute__((ext_vector_type(2)));
typedef u32 u32x4 __attribute__((ext_vector_type(4)));

#define MFMA __builtin_amdgcn_mfma_f32_16x16x32_bf16

__device__ __forceinline__ short f2bf(float f) {
    u32 u = __builtin_bit_cast(u32, f);
    u += 0x7fffu + ((u >> 16) & 1u);
    return (short)(u >> 16);
}
__device__ __forceinline__ u32 pack2(float a, float b) {
    return (u32)(unsigned short)f2bf(a) | ((u32)(unsigned short)f2bf(b) << 16);
}

union FragU { u32 w[4]; bf16x8 v; };
// C-layout regs (k on slots g*8+{0,1,2,3}) -> K-padded fragment, slots 4..7 = 0.
__device__ __forceinline__ bf16x8 padfrag(u32 a, u32 b) {
    FragU f; f.w[0] = a; f.w[1] = b; f.w[2] = 0u; f.w[3] = 0u; return f.v;
}

// ---- pass0: blocks 0..863: coalesced x read, rmsnorm, bf16 xnT[pos][64] via LDS.
//      block 864: weight prep (g_in folded into w_qkv). ----
__global__ __launch_bounds__(256, 4) void la_pass0(
    const float* __restrict__ x, const float* __restrict__ g_in,
    const float* __restrict__ wqkv, const float* __restrict__ wout,
    short* __restrict__ xnT, short* __restrict__ wqkv_bf, short* __restrict__ wout_bf)
{
    const int tid = threadIdx.x;
    const int blk = blockIdx.x;
    if (blk == 864) {
        for (int i = tid; i < 24576; i += 256) wqkv_bf[i] = f2bf(wqkv[i] * g_in[i & 63]);
        for (int i = tid; i < 8192;  i += 256) wout_bf[i] = f2bf(wout[i]);
        return;
    }
    __shared__ __align__(16) char lds[32768];
    const int batch = blk / 432;
    const int pb = (blk % 432) * 256;

    const float* base = x + (size_t)batch * 64 * NPOS + pb + tid;
    float xv[64]; float ss = 0.f;
#pragma unroll
    for (int c = 0; c < 64; ++c) { float t = base[(size_t)c * NPOS]; xv[c] = t; ss += t * t; }
    float rn = 8.0f / fmaxf(sqrtf(ss), 1e-12f);

    char* row = lds + tid * 128;
#pragma unroll
    for (int ch = 0; ch < 8; ++ch) {
        u32x4 w;
        w.x = pack2(xv[ch*8+0] * rn, xv[ch*8+1] * rn);
        w.y = pack2(xv[ch*8+2] * rn, xv[ch*8+3] * rn);
        w.z = pack2(xv[ch*8+4] * rn, xv[ch*8+5] * rn);
        w.w = pack2(xv[ch*8+6] * rn, xv[ch*8+7] * rn);
        *(u32x4*)(row + ((ch ^ (tid & 7)) << 4)) = w;
    }
    __syncthreads();
    char* dst = (char*)xnT + ((size_t)batch * NPOS + pb) * 128;
#pragma unroll
    for (int i = 0; i < 8; ++i) {
        int u = i * 256 + tid;
        int r = u >> 3, cl = u & 7;
        u32x4 w = *(const u32x4*)(lds + r * 128 + ((cl ^ (r & 7)) << 4));
        *(u32x4*)(dst + (size_t)u * 16) = w;
    }
}

// ---- pass1: wave = 2 chunks x 2 heads. K/V GEMM -> exp -> PADDED ctx MFMA (no shuffles)
//      -> reg accum -> LDS combine -> per-block partial (stored in d_out scratch). ----
__global__ __launch_bounds__(256, 4) void la_pass1(
    const short* __restrict__ xnT, const short* __restrict__ wkv,
    float* __restrict__ partials)
{
    __shared__ float lctx[4][2][32][33];
    __shared__ float lz[4][2][32];
    const int tid = threadIdx.x, lane = tid & 63, wid = tid >> 6;
    const int g = lane >> 4, m = lane & 15;
    const int blk = blockIdx.x;
    const int batch = blk / 864;
    const int cb = blk % 864;
    const int CB = cb * 4 + (wid >> 1) * 2;   // this wave: chunks CB, CB+1
    const int hbase = (wid & 1) * 2;          // heads {0,1} or {2,3}
    const short* xb = xnT + (size_t)batch * NPOS * 64;

    f32x4 acc[2][2][2];   // [hh][dt][et]
#pragma unroll
    for (int hh = 0; hh < 2; ++hh)
#pragma unroll
        for (int dt = 0; dt < 2; ++dt)
#pragma unroll
            for (int et = 0; et < 2; ++et) acc[hh][dt][et] = (f32x4){0.f, 0.f, 0.f, 0.f};
    float zacc[2][2] = {{0.f, 0.f}, {0.f, 0.f}};

#pragma unroll 1
    for (int ic = 0; ic < 2; ++ic) {
        const short* p = xb + (size_t)(CB + ic) * 32 * 64;
        bf16x8 af[2][2];
#pragma unroll
        for (int mt = 0; mt < 2; ++mt)
#pragma unroll
            for (int kf = 0; kf < 2; ++kf)
                af[mt][kf] = *(const bf16x8*)(p + (mt * 16 + m) * 64 + kf * 32 + g * 8);

#pragma unroll
        for (int hh = 0; hh < 2; ++hh) {
            const int h = hbase + hh;
            u32 ek[2][2][2], vv[2][2][2];   // [tile][mt][q]  (C[p][.]: p=g*4+r, .=m)
#pragma unroll
            for (int dt = 0; dt < 2; ++dt) {
                const short* wr = wkv + (size_t)(128 + h * 32 + dt * 16 + m) * 64 + g * 8;
                bf16x8 w0 = *(const bf16x8*)wr;
                bf16x8 w1 = *(const bf16x8*)(wr + 32);
#pragma unroll
                for (int mt = 0; mt < 2; ++mt) {
                    f32x4 a = {0.f, 0.f, 0.f, 0.f};
                    a = MFMA(af[mt][0], w0, a, 0, 0, 0);
                    a = MFMA(af[mt][1], w1, a, 0, 0, 0);
                    float e0 = __expf(a[0]), e1 = __expf(a[1]);
                    float e2 = __expf(a[2]), e3 = __expf(a[3]);
                    zacc[hh][dt] += (e0 + e1) + (e2 + e3);
                    ek[dt][mt][0] = pack2(e0, e1);
                    ek[dt][mt][1] = pack2(e2, e3);
                }
            }
#pragma unroll
            for (int et = 0; et < 2; ++et) {
                const short* wr = wkv + (size_t)(256 + h * 32 + et * 16 + m) * 64 + g * 8;
                bf16x8 w0 = *(const bf16x8*)wr;
                bf16x8 w1 = *(const bf16x8*)(wr + 32);
#pragma unroll
                for (int mt = 0; mt < 2; ++mt) {
                    f32x4 a = {0.f, 0.f, 0.f, 0.f};
                    a = MFMA(af[mt][0], w0, a, 0, 0, 0);
                    a = MFMA(af[mt][1], w1, a, 0, 0, 0);
                    vv[et][mt][0] = pack2(a[0], a[1]);
                    vv[et][mt][1] = pack2(a[2], a[3]);
                }
            }
            // ctx[d][e] += sum_p ek[p][d] * v[p][e]  (contract p = C-row, slot-paired)
#pragma unroll
            for (int dt = 0; dt < 2; ++dt)
#pragma unroll
                for (int et = 0; et < 2; ++et)
#pragma unroll
                    for (int mt = 0; mt < 2; ++mt)
                        acc[hh][dt][et] = MFMA(padfrag(ek[dt][mt][0], ek[dt][mt][1]),
                                               padfrag(vv[et][mt][0], vv[et][mt][1]),
                                               acc[hh][dt][et], 0, 0, 0);
        }
    }

    // combine 4 waves via LDS, store per-block partial
#pragma unroll
    for (int hh = 0; hh < 2; ++hh) {
#pragma unroll
        for (int dt = 0; dt < 2; ++dt)
#pragma unroll
            for (int et = 0; et < 2; ++et)
#pragma unroll
                for (int r = 0; r < 4; ++r)
                    lctx[wid][hh][dt * 16 + g * 4 + r][et * 16 + m] = acc[hh][dt][et][r];
#pragma unroll
        for (int dt = 0; dt < 2; ++dt) {
            float z = zacc[hh][dt];
            z += __shfl_xor(z, 16);
            z += __shfl_xor(z, 32);
            if (g == 0) lz[wid][hh][dt * 16 + m] = z;
        }
    }
    __syncthreads();

    float* P = partials + (size_t)blk * 4224;
    for (int i = tid; i < 4096; i += 256) {
        int h = i >> 10, de = i & 1023, d = de >> 5, e = de & 31;
        int w0 = h >> 1, hh = h & 1;
        P[i] = lctx[w0][hh][d][e] + lctx[w0 + 2][hh][d][e];
    }
    if (tid < 128) {
        int h = tid >> 5, d = tid & 31;
        P[4096 + tid] = lz[h >> 1][h & 1][d] + lz[(h >> 1) + 2][h & 1][d];
    }
}

// ---- ctxt stage A: reduce 864 partials/batch -> 32 groups of 27 ----
__global__ __launch_bounds__(256) void la_ctxt_a(const float* __restrict__ partials,
                                                 float* __restrict__ part2)
{
    int t = blockIdx.x * 256 + threadIdx.x;       // 2*32*4224 = 270336 exactly
    int b = t / 135168;
    int rem = t % 135168;
    int grp = rem / 4224;
    int i = rem % 4224;
    const float* P = partials + ((size_t)(b * 864 + grp * 27)) * 4224 + i;
    float s = 0.f;
#pragma unroll 3
    for (int j = 0; j < 27; ++j) s += P[(size_t)j * 4224];
    part2[((size_t)(b * 32 + grp)) * 4224 + i] = s;
}

// ---- ctxt stage B: one block per (b,h): final sum + mem_kv fold + emit ctxA frags ----
__global__ __launch_bounds__(256) void la_ctxt_b(const float* __restrict__ part2,
                                                 const float* __restrict__ mem_kv,
                                                 u32* __restrict__ ctxA)
{
    __shared__ float ctxN[32][33];
    const int tid = threadIdx.x;
    const int b = blockIdx.x >> 2, h = blockIdx.x & 3;
    const float* P = part2 + (size_t)b * 32 * 4224;
#pragma unroll
    for (int u = 0; u < 4; ++u) {
        int de = tid * 4 + u;
        int d = de >> 5, e = de & 31;
        float S = 0.f, Z = 0.f;
#pragma unroll 4
        for (int grp = 0; grp < 32; ++grp) {
            S += P[(size_t)grp * 4224 + h * 1024 + de];
            Z += P[(size_t)grp * 4224 + 4096 + h * 32 + d];
        }
        const float* mk = mem_kv + (h * 32 + d) * 4;
        const float* mv = mem_kv + 512 + (h * 32 + e) * 4;
#pragma unroll
        for (int mm = 0; mm < 4; ++mm) {
            float ekv = __expf(mk[mm]);
            S += ekv * mv[mm];
            Z += ekv;
        }
        ctxN[d][e] = S / Z;
    }
    __syncthreads();
    // emit A-frag layout: ctxA[(b*4+h)*512 + et*256 + dt*128 + lane*2 + q]
    //   = pack2(ctx[dt*16+g*4+2q][et*16+mm], ctx[dt*16+g*4+2q+1][et*16+mm])
#pragma unroll
    for (int k = 0; k < 2; ++k) {
        int j = tid * 2 + k;                  // 0..511
        int q = j & 1, lanej = (j >> 1) & 63, dt = (j >> 7) & 1, et = (j >> 8) & 1;
        int gg = lanej >> 4, mm = lanej & 15;
        int d0 = dt * 16 + gg * 4 + 2 * q, e = et * 16 + mm;
        ctxA[(size_t)(b * 4 + h) * 512 + j] = pack2(ctxN[d0][e], ctxN[d0 + 1][e]);
    }
}

// ---- pass2: Q swapped -> exp -> hid (padded, contract d) -> wout (padded, contract e)
//      -> rmsnorm -> store. Zero shuffles except denominator + epilogue. ----
__global__ __launch_bounds__(256, 4) void la_pass2(
    const short* __restrict__ xnT, const short* __restrict__ wq,
    const u32* __restrict__ ctxA, const short* __restrict__ wout,
    const float* __restrict__ b_out, const float* __restrict__ g_out,
    float* __restrict__ out)
{
    const int tid = threadIdx.x, lane = tid & 63, wid = tid >> 6;
    const int g = lane >> 4, m = lane & 15;
    const int blk = blockIdx.x;
    const int batch = blk / 864;
    const int cq = (blk % 864) * 4 + wid;     // [0, 3456)
    const int posbase = cq * 32;

    const short* xp = xnT + ((size_t)batch * NPOS + posbase) * 64;
    bf16x8 af[2][2];
#pragma unroll
    for (int mt = 0; mt < 2; ++mt)
#pragma unroll
        for (int kf = 0; kf < 2; ++kf)
            af[mt][kf] = *(const bf16x8*)(xp + (mt * 16 + m) * 64 + kf * 32 + g * 8);

    f32x4 oacc[4][2];
#pragma unroll
    for (int ct = 0; ct < 4; ++ct)
#pragma unroll
        for (int mt = 0; mt < 2; ++mt) oacc[ct][mt] = (f32x4){0.f, 0.f, 0.f, 0.f};

    const float scale = 0.17677669529663687f;   // 32^-0.5
    const u32* cab = ctxA + (size_t)batch * 4 * 512;

#pragma unroll 1
    for (int h = 0; h < 4; ++h) {
        // EQ = exp(Wq . Xn^T): C[d][p], d on (g,r), p on m
        u32 eqB[2][2][2];   // [dt][mt][q]
        float dpart[2] = {0.f, 0.f};
#pragma unroll
        for (int dt = 0; dt < 2; ++dt) {
            const short* wr = wq + (size_t)(h * 32 + dt * 16 + m) * 64 + g * 8;
            bf16x8 a0 = *(const bf16x8*)wr;
            bf16x8 a1 = *(const bf16x8*)(wr + 32);
#pragma unroll
            for (int mt = 0; mt < 2; ++mt) {
                f32x4 a = {0.f, 0.f, 0.f, 0.f};
                a = MFMA(a0, af[mt][0], a, 0, 0, 0);
                a = MFMA(a1, af[mt][1], a, 0, 0, 0);
                float e0 = __expf(a[0]), e1 = __expf(a[1]);
                float e2 = __expf(a[2]), e3 = __expf(a[3]);
                dpart[mt] += (e0 + e1) + (e2 + e3);
                eqB[dt][mt][0] = pack2(e0, e1);
                eqB[dt][mt][1] = pack2(e2, e3);
            }
        }
        float inv[2];
#pragma unroll
        for (int mt = 0; mt < 2; ++mt) {
            float dn = dpart[mt];
            dn += __shfl_xor(dn, 16);
            dn += __shfl_xor(dn, 32);
            inv[mt] = scale / dn;
        }
        // hid[e][p] = sum_d ctx[d][e]*EQ[d][p] (contract d = C-row of EQ)
        u32 hidB[2][2][2];  // [et][mt][q]
#pragma unroll
        for (int et = 0; et < 2; ++et) {
            u32x2 c0 = *(const u32x2*)(cab + h * 512 + et * 256 + 0 * 128 + lane * 2);
            u32x2 c1 = *(const u32x2*)(cab + h * 512 + et * 256 + 1 * 128 + lane * 2);
#pragma unroll
            for (int mt = 0; mt < 2; ++mt) {
                f32x4 hh2 = {0.f, 0.f, 0.f, 0.f};
                hh2 = MFMA(padfrag(c0.x, c0.y), padfrag(eqB[0][mt][0], eqB[0][mt][1]), hh2, 0, 0, 0);
                hh2 = MFMA(padfrag(c1.x, c1.y), padfrag(eqB[1][mt][0], eqB[1][mt][1]), hh2, 0, 0, 0);
                hidB[et][mt][0] = pack2(hh2[0] * inv[mt], hh2[1] * inv[mt]);
                hidB[et][mt][1] = pack2(hh2[2] * inv[mt], hh2[3] * inv[mt]);
            }
        }
        // out[c][p] += sum_e wout[c][e]*hid[e][p] (contract e = C-row of hid)
#pragma unroll
        for (int ct = 0; ct < 4; ++ct)
#pragma unroll
            for (int et = 0; et < 2; ++et) {
                u32x2 wv = *(const u32x2*)(wout + (size_t)(ct * 16 + m) * 128
                                           + h * 32 + et * 16 + g * 4);
                bf16x8 wfr = padfrag(wv.x, wv.y);
#pragma unroll
                for (int mt = 0; mt < 2; ++mt)
                    oacc[ct][mt] = MFMA(wfr, padfrag(hidB[et][mt][0], hidB[et][mt][1]),
                                        oacc[ct][mt], 0, 0, 0);
            }
    }

    // epilogue: +b_out, rmsnorm over c, *g_out, store (c = ct*16+g*4+r, p = posbase+mt*16+m)
    float bo[4][4], go[4][4];
#pragma unroll
    for (int ct = 0; ct < 4; ++ct)
#pragma unroll
        for (int r = 0; r < 4; ++r) {
            int c = ct * 16 + g * 4 + r;
            bo[ct][r] = b_out[c];
            go[ct][r] = g_out[c];
        }
    float* ob = out + (size_t)batch * 64 * NPOS;
#pragma unroll
    for (int mt = 0; mt < 2; ++mt) {
        float vv[4][4]; float s2 = 0.f;
#pragma unroll
        for (int ct = 0; ct < 4; ++ct)
#pragma unroll
            for (int r = 0; r < 4; ++r) {
                float v = oacc[ct][mt][r] + bo[ct][r];
                vv[ct][r] = v;
                s2 += v * v;
            }
        s2 += __shfl_xor(s2, 16);
        s2 += __shfl_xor(s2, 32);
        float rn2 = 8.0f / fmaxf(sqrtf(s2), 1e-12f);
        int pn = posbase + mt * 16 + m;
#pragma unroll
        for (int ct = 0; ct < 4; ++ct)
#pragma unroll
            for (int r = 0; r < 4; ++r)
                ob[(size_t)(ct * 16 + g * 4 + r) * NPOS + pn] = vv[ct][r] * rn2 * go[ct][r];
    }
}

extern "C" void kernel_launch(void* const* d_in, const int* in_sizes, int n_in,
                              void* d_out, int out_size, void* d_ws, size_t ws_size,
                              hipStream_t stream) {
    const float* x      = (const float*)d_in[0];
    const float* g_in   = (const float*)d_in[1];
    const float* w_qkv  = (const float*)d_in[2];
    const float* mem_kv = (const float*)d_in[3];
    const float* w_out  = (const float*)d_in[4];
    const float* b_out  = (const float*)d_in[5];
    const float* g_out  = (const float*)d_in[6];
    float* out = (float*)d_out;

    char* ws = (char*)d_ws;
    short* xnT     = (short*)(ws);                 // 28,311,552 B
    float* part2   = (float*)(ws + 28311552);      //  1,081,344 B
    short* wqkv_bf = (short*)(ws + 29392896);      //     49,152 B
    short* wout_bf = (short*)(ws + 29442048);      //     16,384 B
    u32*   ctxA    = (u32*)  (ws + 29458432);      //     16,384 B  (end ~29.5 MB)

    // pass1 partials (1728*4224 f32 = 29.2 MB) live in d_out scratch; fully
    // consumed by la_ctxt_a before la_pass2 overwrites d_out with the output.
    float* partials = (float*)d_out;

    la_pass0<<<865, 256, 0, stream>>>(x, g_in, w_qkv, w_out, xnT, wqkv_bf, wout_bf);
    la_pass1<<<1728, 256, 0, stream>>>(xnT, wqkv_bf, partials);
    la_ctxt_a<<<1056, 256, 0, stream>>>(partials, part2);
    la_ctxt_b<<<8, 256, 0, stream>>>(part2, mem_kv, ctxA);
    la_pass2<<<1728, 256, 0, stream>>>(xnT, wqkv_bf, ctxA, wout_bf, b_out, g_out, out);
}

// Round 8
// 108.995 us; speedup vs baseline: 2.5278x; 1.3354x over previous
//
#include <hip/hip_runtime.h>
#include <math.h>

#define NPOS 110592

typedef float f32x4 __attribute__((ext_vector_type(4)));
typedef short bf16x8 __attribute__((ext_vector_type(8)));
typedef unsigned u32;
typedef u32 u32x2 __attribute__((ext_vector_type(2)));
typedef u32 u32x4 __attribute__((ext_vector_type(4)));

#define MFMA __builtin_amdgcn_mfma_f32_16x16x32_bf16

__device__ __forceinline__ short f2bf(float f) {
    u32 u = __builtin_bit_cast(u32, f);
    u += 0x7fffu + ((u >> 16) & 1u);
    return (short)(u >> 16);
}
// ALU round-to-nearest-even pack (proven rounds 1-6). Do NOT swap for inline-asm
// cvt_pk without an isolated A/B — round 7's NaN regression had it as a suspect.
__device__ __forceinline__ u32 pack2(float a, float b) {
    return (u32)(unsigned short)f2bf(a) | ((u32)(unsigned short)f2bf(b) << 16);
}

union FragU { u32 w[4]; bf16x8 v; };
// C-layout regs (k on slots g*8+{0,1,2,3}) -> K-padded fragment, slots 4..7 = 0.
__device__ __forceinline__ bf16x8 padfrag(u32 a, u32 b) {
    FragU f; f.w[0] = a; f.w[1] = b; f.w[2] = 0u; f.w[3] = 0u; return f.v;
}

// ---- prep: bf16 weights, g_in folded into w_qkv columns ----
__global__ __launch_bounds__(256) void la_prep(const float* __restrict__ wqkv,
                                               const float* __restrict__ g_in,
                                               const float* __restrict__ wout,
                                               short* __restrict__ wqkv_bf,
                                               short* __restrict__ wout_bf)
{
    int i = blockIdx.x * 256 + threadIdx.x;
    if (i < 24576) wqkv_bf[i] = f2bf(wqkv[i] * g_in[i & 63]);
    if (i < 8192)  wout_bf[i] = f2bf(wout[i]);
}

// ---- p01: fused pass0+pass1, conservative rebuild from round-6-proven pieces.
// Phase A: coalesced x read -> rmsnorm -> swizzled LDS stage -> coalesced xnT write.
// Phase B: wave = 4 chunks (128 pos) x 2 heads; af from LDS; K/V GEMM -> exp ->
//          padded ctx MFMA (static acc[2][2][2]); LDS combine (xnz overlaid). ----
__global__ __launch_bounds__(256, 3) void la_p01(
    const float* __restrict__ x, const short* __restrict__ wkv,
    short* __restrict__ xnT, float* __restrict__ partials)
{
    __shared__ __align__(16) char smem[34816];
    char* xnz = smem;                                              // 32768 B, phase A/B
    float (*lctx)[2][32][33] = (float (*)[2][32][33])smem;         // 33792 B, phase C
    float (*lz)[2][32]       = (float (*)[2][32])(smem + 33792);   //  1024 B, phase C

    const int tid = threadIdx.x, lane = tid & 63, wid = tid >> 6;
    const int g = lane >> 4, m = lane & 15;
    const int blk = blockIdx.x;
    const int batch = blk / 432;
    const int pb = (blk % 432) * 256;

    // A1. coalesced x read + in-thread rmsnorm
    const float* base = x + (size_t)batch * 64 * NPOS + pb + tid;
    float xv[64]; float ss = 0.f;
#pragma unroll
    for (int c = 0; c < 64; ++c) { float t = base[(size_t)c * NPOS]; xv[c] = t; ss += t * t; }
    float rn = 8.0f / fmaxf(sqrtf(ss), 1e-12f);

    // A2. stage bf16 row, 16B chunks XOR-swizzled (proven round 6)
    char* row = xnz + tid * 128;
#pragma unroll
    for (int ch = 0; ch < 8; ++ch) {
        u32x4 w;
        w.x = pack2(xv[ch*8+0] * rn, xv[ch*8+1] * rn);
        w.y = pack2(xv[ch*8+2] * rn, xv[ch*8+3] * rn);
        w.z = pack2(xv[ch*8+4] * rn, xv[ch*8+5] * rn);
        w.w = pack2(xv[ch*8+6] * rn, xv[ch*8+7] * rn);
        *(u32x4*)(row + ((ch ^ (tid & 7)) << 4)) = w;
    }
    __syncthreads();

    // A3. coalesced xnT write for pass2 (identical to round 6)
    char* dst = (char*)xnT + ((size_t)batch * NPOS + pb) * 128;
#pragma unroll
    for (int i = 0; i < 8; ++i) {
        int u = i * 256 + tid;
        int r = u >> 3, cl = u & 7;
        u32x4 w = *(const u32x4*)(xnz + r * 128 + ((cl ^ (r & 7)) << 4));
        *(u32x4*)(dst + (size_t)u * 16) = w;
    }

    // B. compute: wave wid -> chunk group cg = wid>>1 (positions cg*128..+128),
    //    head pair hbase = (wid&1)*2. Exactly round-6 pass1's register structure.
    const int cg = wid >> 1, hbase = (wid & 1) * 2;

    f32x4 acc[2][2][2];   // [hh][dt][et] - all static indices
#pragma unroll
    for (int hh = 0; hh < 2; ++hh)
#pragma unroll
        for (int dt = 0; dt < 2; ++dt)
#pragma unroll
            for (int et = 0; et < 2; ++et) acc[hh][dt][et] = (f32x4){0.f, 0.f, 0.f, 0.f};
    float zacc[2][2] = {{0.f, 0.f}, {0.f, 0.f}};

#pragma unroll 1
    for (int ic = 0; ic < 4; ++ic) {
        bf16x8 af[2][2];
#pragma unroll
        for (int mt = 0; mt < 2; ++mt)
#pragma unroll
            for (int kf = 0; kf < 2; ++kf) {
                int rowi = cg * 128 + ic * 32 + mt * 16 + m;
                af[mt][kf] = *(const bf16x8*)(xnz + rowi * 128 + (((kf*4+g) ^ (rowi & 7)) << 4));
            }
#pragma unroll
        for (int hh = 0; hh < 2; ++hh) {
            const int h = hbase + hh;
            u32 ek[2][2][2], vv[2][2][2];
#pragma unroll
            for (int dt = 0; dt < 2; ++dt) {
                const short* wr = wkv + (size_t)(128 + h * 32 + dt * 16 + m) * 64 + g * 8;
                bf16x8 w0 = *(const bf16x8*)wr;
                bf16x8 w1 = *(const bf16x8*)(wr + 32);
#pragma unroll
                for (int mt = 0; mt < 2; ++mt) {
                    f32x4 a = {0.f, 0.f, 0.f, 0.f};
                    a = MFMA(af[mt][0], w0, a, 0, 0, 0);
                    a = MFMA(af[mt][1], w1, a, 0, 0, 0);
                    float e0 = __expf(a[0]), e1 = __expf(a[1]);
                    float e2 = __expf(a[2]), e3 = __expf(a[3]);
                    zacc[hh][dt] += (e0 + e1) + (e2 + e3);
                    ek[dt][mt][0] = pack2(e0, e1);
                    ek[dt][mt][1] = pack2(e2, e3);
                }
            }
#pragma unroll
            for (int et = 0; et < 2; ++et) {
                const short* wr = wkv + (size_t)(256 + h * 32 + et * 16 + m) * 64 + g * 8;
                bf16x8 w0 = *(const bf16x8*)wr;
                bf16x8 w1 = *(const bf16x8*)(wr + 32);
#pragma unroll
                for (int mt = 0; mt < 2; ++mt) {
                    f32x4 a = {0.f, 0.f, 0.f, 0.f};
                    a = MFMA(af[mt][0], w0, a, 0, 0, 0);
                    a = MFMA(af[mt][1], w1, a, 0, 0, 0);
                    vv[et][mt][0] = pack2(a[0], a[1]);
                    vv[et][mt][1] = pack2(a[2], a[3]);
                }
            }
#pragma unroll
            for (int dt = 0; dt < 2; ++dt)
#pragma unroll
                for (int et = 0; et < 2; ++et)
#pragma unroll
                    for (int mt = 0; mt < 2; ++mt)
                        acc[hh][dt][et] = MFMA(padfrag(ek[dt][mt][0], ek[dt][mt][1]),
                                               padfrag(vv[et][mt][0], vv[et][mt][1]),
                                               acc[hh][dt][et], 0, 0, 0);
        }
    }

    // C. combine (round-6 code). Barrier first: xnz reads (phase B) must complete
    //    before lctx overlays the same LDS.
    __syncthreads();
#pragma unroll
    for (int hh = 0; hh < 2; ++hh) {
#pragma unroll
        for (int dt = 0; dt < 2; ++dt) {
#pragma unroll
            for (int et = 0; et < 2; ++et)
#pragma unroll
                for (int r4 = 0; r4 < 4; ++r4)
                    lctx[wid][hh][dt * 16 + g * 4 + r4][et * 16 + m] = acc[hh][dt][et][r4];
            float z = zacc[hh][dt];
            z += __shfl_xor(z, 16);
            z += __shfl_xor(z, 32);
            if (g == 0) lz[wid][hh][dt * 16 + m] = z;
        }
    }
    __syncthreads();

    float* P = partials + (size_t)blk * 4224;
    for (int i = tid; i < 4096; i += 256) {
        int h = i >> 10, de = i & 1023, d = de >> 5, e = de & 31;
        int w0 = h >> 1, hh2 = h & 1;
        P[i] = lctx[w0][hh2][d][e] + lctx[w0 + 2][hh2][d][e];
    }
    if (tid < 128) {
        int h = tid >> 5, d = tid & 31;
        P[4096 + tid] = lz[h >> 1][h & 1][d] + lz[(h >> 1) + 2][h & 1][d];
    }
}

// ---- ctxt stage A: reduce 432 partials/batch -> 16 groups of 27 ----
__global__ __launch_bounds__(256) void la_ctxt_a(const float* __restrict__ partials,
                                                 float* __restrict__ part2)
{
    int t = blockIdx.x * 256 + threadIdx.x;       // 2*16*4224 = 135168 exactly
    int b = t / 67584;
    int rem = t % 67584;
    int grp = rem / 4224;
    int i = rem % 4224;
    const float* P = partials + ((size_t)(b * 432 + grp * 27)) * 4224 + i;
    float s = 0.f;
#pragma unroll 3
    for (int j = 0; j < 27; ++j) s += P[(size_t)j * 4224];
    part2[((size_t)(b * 16 + grp)) * 4224 + i] = s;
}

// ---- ctxt stage B: one block per (b,h): final sum + mem_kv fold + emit ctxA frags ----
__global__ __launch_bounds__(256) void la_ctxt_b(const float* __restrict__ part2,
                                                 const float* __restrict__ mem_kv,
                                                 u32* __restrict__ ctxA)
{
    __shared__ float ctxN[32][33];
    const int tid = threadIdx.x;
    const int b = blockIdx.x >> 2, h = blockIdx.x & 3;
    const float* P = part2 + (size_t)b * 16 * 4224;
#pragma unroll
    for (int u = 0; u < 4; ++u) {
        int de = tid * 4 + u;
        int d = de >> 5, e = de & 31;
        float S = 0.f, Z = 0.f;
#pragma unroll 4
        for (int grp = 0; grp < 16; ++grp) {
            S += P[(size_t)grp * 4224 + h * 1024 + de];
            Z += P[(size_t)grp * 4224 + 4096 + h * 32 + d];
        }
        const float* mk = mem_kv + (h * 32 + d) * 4;
        const float* mv = mem_kv + 512 + (h * 32 + e) * 4;
#pragma unroll
        for (int mm = 0; mm < 4; ++mm) {
            float ekv = __expf(mk[mm]);
            S += ekv * mv[mm];
            Z += ekv;
        }
        ctxN[d][e] = S / Z;
    }
    __syncthreads();
    // emit A-frag layout: ctxA[(b*4+h)*512 + et*256 + dt*128 + lane*2 + q]
#pragma unroll
    for (int k = 0; k < 2; ++k) {
        int j = tid * 2 + k;                  // 0..511
        int q = j & 1, lanej = (j >> 1) & 63, dt = (j >> 7) & 1, et = (j >> 8) & 1;
        int gg = lanej >> 4, mm = lanej & 15;
        int d0 = dt * 16 + gg * 4 + 2 * q, e = et * 16 + mm;
        ctxA[(size_t)(b * 4 + h) * 512 + j] = pack2(ctxN[d0][e], ctxN[d0 + 1][e]);
    }
}

// ---- pass2: verbatim round 6 (passed, 58 us). Q swapped -> exp -> hid -> wout ->
//      rmsnorm -> store. ----
__global__ __launch_bounds__(256, 4) void la_pass2(
    const short* __restrict__ xnT, const short* __restrict__ wq,
    const u32* __restrict__ ctxA, const short* __restrict__ wout,
    const float* __restrict__ b_out, const float* __restrict__ g_out,
    float* __restrict__ out)
{
    const int tid = threadIdx.x, lane = tid & 63, wid = tid >> 6;
    const int g = lane >> 4, m = lane & 15;
    const int blk = blockIdx.x;
    const int batch = blk / 864;
    const int cq = (blk % 864) * 4 + wid;     // [0, 3456)
    const int posbase = cq * 32;

    const short* xp = xnT + ((size_t)batch * NPOS + posbase) * 64;
    bf16x8 af[2][2];
#pragma unroll
    for (int mt = 0; mt < 2; ++mt)
#pragma unroll
        for (int kf = 0; kf < 2; ++kf)
            af[mt][kf] = *(const bf16x8*)(xp + (mt * 16 + m) * 64 + kf * 32 + g * 8);

    f32x4 oacc[4][2];
#pragma unroll
    for (int ct = 0; ct < 4; ++ct)
#pragma unroll
        for (int mt = 0; mt < 2; ++mt) oacc[ct][mt] = (f32x4){0.f, 0.f, 0.f, 0.f};

    const float scale = 0.17677669529663687f;   // 32^-0.5
    const u32* cab = ctxA + (size_t)batch * 4 * 512;

#pragma unroll 1
    for (int h = 0; h < 4; ++h) {
        // EQ = exp(Wq . Xn^T): C[d][p], d on (g,r), p on m
        u32 eqB[2][2][2];   // [dt][mt][q]
        float dpart[2] = {0.f, 0.f};
#pragma unroll
        for (int dt = 0; dt < 2; ++dt) {
            const short* wr = wq + (size_t)(h * 32 + dt * 16 + m) * 64 + g * 8;
            bf16x8 a0 = *(const bf16x8*)wr;
            bf16x8 a1 = *(const bf16x8*)(wr + 32);
#pragma unroll
            for (int mt = 0; mt < 2; ++mt) {
                f32x4 a = {0.f, 0.f, 0.f, 0.f};
                a = MFMA(a0, af[mt][0], a, 0, 0, 0);
                a = MFMA(a1, af[mt][1], a, 0, 0, 0);
                float e0 = __expf(a[0]), e1 = __expf(a[1]);
                float e2 = __expf(a[2]), e3 = __expf(a[3]);
                dpart[mt] += (e0 + e1) + (e2 + e3);
                eqB[dt][mt][0] = pack2(e0, e1);
                eqB[dt][mt][1] = pack2(e2, e3);
            }
        }
        float inv[2];
#pragma unroll
        for (int mt = 0; mt < 2; ++mt) {
            float dn = dpart[mt];
            dn += __shfl_xor(dn, 16);
            dn += __shfl_xor(dn, 32);
            inv[mt] = scale / dn;
        }
        // hid[e][p] = sum_d ctx[d][e]*EQ[d][p] (contract d = C-row of EQ)
        u32 hidB[2][2][2];  // [et][mt][q]
#pragma unroll
        for (int et = 0; et < 2; ++et) {
            u32x2 c0 = *(const u32x2*)(cab + h * 512 + et * 256 + 0 * 128 + lane * 2);
            u32x2 c1 = *(const u32x2*)(cab + h * 512 + et * 256 + 1 * 128 + lane * 2);
#pragma unroll
            for (int mt = 0; mt < 2; ++mt) {
                f32x4 hh2 = {0.f, 0.f, 0.f, 0.f};
                hh2 = MFMA(padfrag(c0.x, c0.y), padfrag(eqB[0][mt][0], eqB[0][mt][1]), hh2, 0, 0, 0);
                hh2 = MFMA(padfrag(c1.x, c1.y), padfrag(eqB[1][mt][0], eqB[1][mt][1]), hh2, 0, 0, 0);
                hidB[et][mt][0] = pack2(hh2[0] * inv[mt], hh2[1] * inv[mt]);
                hidB[et][mt][1] = pack2(hh2[2] * inv[mt], hh2[3] * inv[mt]);
            }
        }
        // out[c][p] += sum_e wout[c][e]*hid[e][p] (contract e = C-row of hid)
#pragma unroll
        for (int ct = 0; ct < 4; ++ct)
#pragma unroll
            for (int et = 0; et < 2; ++et) {
                u32x2 wv = *(const u32x2*)(wout + (size_t)(ct * 16 + m) * 128
                                           + h * 32 + et * 16 + g * 4);
                bf16x8 wfr = padfrag(wv.x, wv.y);
#pragma unroll
                for (int mt = 0; mt < 2; ++mt)
                    oacc[ct][mt] = MFMA(wfr, padfrag(hidB[et][mt][0], hidB[et][mt][1]),
                                        oacc[ct][mt], 0, 0, 0);
            }
    }

    // epilogue: +b_out, rmsnorm over c, *g_out, store (c = ct*16+g*4+r, p = posbase+mt*16+m)
    float bo[4][4], go[4][4];
#pragma unroll
    for (int ct = 0; ct < 4; ++ct)
#pragma unroll
        for (int r = 0; r < 4; ++r) {
            int c = ct * 16 + g * 4 + r;
            bo[ct][r] = b_out[c];
            go[ct][r] = g_out[c];
        }
    float* ob = out + (size_t)batch * 64 * NPOS;
#pragma unroll
    for (int mt = 0; mt < 2; ++mt) {
        float vv[4][4]; float s2 = 0.f;
#pragma unroll
        for (int ct = 0; ct < 4; ++ct)
#pragma unroll
            for (int r = 0; r < 4; ++r) {
                float v = oacc[ct][mt][r] + bo[ct][r];
                vv[ct][r] = v;
                s2 += v * v;
            }
        s2 += __shfl_xor(s2, 16);
        s2 += __shfl_xor(s2, 32);
        float rn2 = 8.0f / fmaxf(sqrtf(s2), 1e-12f);
        int pn = posbase + mt * 16 + m;
#pragma unroll
        for (int ct = 0; ct < 4; ++ct)
#pragma unroll
            for (int r = 0; r < 4; ++r)
                ob[(size_t)(ct * 16 + g * 4 + r) * NPOS + pn] = vv[ct][r] * rn2 * go[ct][r];
    }
}

extern "C" void kernel_launch(void* const* d_in, const int* in_sizes, int n_in,
                              void* d_out, int out_size, void* d_ws, size_t ws_size,
                              hipStream_t stream) {
    const float* x      = (const float*)d_in[0];
    const float* g_in   = (const float*)d_in[1];
    const float* w_qkv  = (const float*)d_in[2];
    const float* mem_kv = (const float*)d_in[3];
    const float* w_out  = (const float*)d_in[4];
    const float* b_out  = (const float*)d_in[5];
    const float* g_out  = (const float*)d_in[6];
    float* out = (float*)d_out;

    char* ws = (char*)d_ws;
    short* xnT     = (short*)(ws);                 // 28,311,552 B
    float* part2   = (float*)(ws + 28311552);      //    540,672 B (2*16*4224 f32)
    short* wqkv_bf = (short*)(ws + 28852224);      //     49,152 B
    short* wout_bf = (short*)(ws + 28901376);      //     16,384 B
    u32*   ctxA    = (u32*)  (ws + 28917760);      //     16,384 B (end ~28.9 MB)

    // p01 partials (864*4224 f32 = 14.6 MB) live in d_out scratch; fully consumed
    // by la_ctxt_a before la_pass2 overwrites d_out with the real output.
    float* partials = (float*)d_out;

    la_prep<<<96, 256, 0, stream>>>(w_qkv, g_in, w_out, wqkv_bf, wout_bf);
    la_p01<<<864, 256, 0, stream>>>(x, wqkv_bf, xnT, partials);
    la_ctxt_a<<<528, 256, 0, stream>>>(partials, part2);
    la_ctxt_b<<<8, 256, 0, stream>>>(part2, mem_kv, ctxA);
    la_pass2<<<1728, 256, 0, stream>>>(xnT, wqkv_bf, ctxA, wout_bf, b_out, g_out, out);
}

// Round 9
// 96.321 us; speedup vs baseline: 2.8604x; 1.1316x over previous
//
#include <hip/hip_runtime.h>
#include <math.h>

#define NPOS 110592

typedef float f32x4 __attribute__((ext_vector_type(4)));
typedef short bf16x8 __attribute__((ext_vector_type(8)));
typedef unsigned u32;
typedef u32 u32x2 __attribute__((ext_vector_type(2)));
typedef u32 u32x4 __attribute__((ext_vector_type(4)));

#define MFMA __builtin_amdgcn_mfma_f32_16x16x32_bf16

__device__ __forceinline__ short f2bf(float f) {
    u32 u = __builtin_bit_cast(u32, f);
    u += 0x7fffu + ((u >> 16) & 1u);
    return (short)(u >> 16);
}
// ALU round-to-nearest-even pack (proven rounds 1-8). Do NOT swap for inline-asm
// cvt_pk without an isolated A/B — round 7's NaN regression had it as a suspect.
__device__ __forceinline__ u32 pack2(float a, float b) {
    return (u32)(unsigned short)f2bf(a) | ((u32)(unsigned short)f2bf(b) << 16);
}

union FragU { u32 w[4]; bf16x8 v; };
// C-layout regs (k on slots g*8+{0,1,2,3}) -> K-padded fragment, slots 4..7 = 0.
__device__ __forceinline__ bf16x8 padfrag(u32 a, u32 b) {
    FragU f; f.w[0] = a; f.w[1] = b; f.w[2] = 0u; f.w[3] = 0u; return f.v;
}

// ---- prep: bf16 weights, g_in folded into w_qkv columns ----
__global__ __launch_bounds__(256) void la_prep(const float* __restrict__ wqkv,
                                               const float* __restrict__ g_in,
                                               const float* __restrict__ wout,
                                               short* __restrict__ wqkv_bf,
                                               short* __restrict__ wout_bf)
{
    int i = blockIdx.x * 256 + threadIdx.x;
    if (i < 24576) wqkv_bf[i] = f2bf(wqkv[i] * g_in[i & 63]);
    if (i < 8192)  wout_bf[i] = f2bf(wout[i]);
}

// ---- p01: fused pass0+pass1 (round-8 structure, wkv fragments hoisted out of ic loop).
__global__ __launch_bounds__(256, 3) void la_p01(
    const float* __restrict__ x, const short* __restrict__ wkv,
    short* __restrict__ xnT, float* __restrict__ partials)
{
    __shared__ __align__(16) char smem[34816];
    char* xnz = smem;                                              // 32768 B, phase A/B
    float (*lctx)[2][32][33] = (float (*)[2][32][33])smem;         // 33792 B, phase C
    float (*lz)[2][32]       = (float (*)[2][32])(smem + 33792);   //  1024 B, phase C

    const int tid = threadIdx.x, lane = tid & 63, wid = tid >> 6;
    const int g = lane >> 4, m = lane & 15;
    const int blk = blockIdx.x;
    const int batch = blk / 432;
    const int pb = (blk % 432) * 256;

    // A1. coalesced x read + in-thread rmsnorm
    const float* base = x + (size_t)batch * 64 * NPOS + pb + tid;
    float xv[64]; float ss = 0.f;
#pragma unroll
    for (int c = 0; c < 64; ++c) { float t = base[(size_t)c * NPOS]; xv[c] = t; ss += t * t; }
    float rn = 8.0f / fmaxf(sqrtf(ss), 1e-12f);

    // A2. stage bf16 row, 16B chunks XOR-swizzled
    char* row = xnz + tid * 128;
#pragma unroll
    for (int ch = 0; ch < 8; ++ch) {
        u32x4 w;
        w.x = pack2(xv[ch*8+0] * rn, xv[ch*8+1] * rn);
        w.y = pack2(xv[ch*8+2] * rn, xv[ch*8+3] * rn);
        w.z = pack2(xv[ch*8+4] * rn, xv[ch*8+5] * rn);
        w.w = pack2(xv[ch*8+6] * rn, xv[ch*8+7] * rn);
        *(u32x4*)(row + ((ch ^ (tid & 7)) << 4)) = w;
    }
    __syncthreads();

    // A3. coalesced xnT write for pass2
    char* dst = (char*)xnT + ((size_t)batch * NPOS + pb) * 128;
#pragma unroll
    for (int i = 0; i < 8; ++i) {
        int u = i * 256 + tid;
        int r = u >> 3, cl = u & 7;
        u32x4 w = *(const u32x4*)(xnz + r * 128 + ((cl ^ (r & 7)) << 4));
        *(u32x4*)(dst + (size_t)u * 16) = w;
    }

    // B. compute: wave wid -> chunk group cg (128 pos), head pair hbase.
    const int cg = wid >> 1, hbase = (wid & 1) * 2;

    // Hoisted weight fragments (static indices; loaded once per wave, not per ic)
    bf16x8 wkA[2][2][2], wvA[2][2][2];   // [hh][tile][half]
#pragma unroll
    for (int hh = 0; hh < 2; ++hh) {
#pragma unroll
        for (int dt = 0; dt < 2; ++dt) {
            const short* wr = wkv + (size_t)(128 + (hbase + hh) * 32 + dt * 16 + m) * 64 + g * 8;
            wkA[hh][dt][0] = *(const bf16x8*)wr;
            wkA[hh][dt][1] = *(const bf16x8*)(wr + 32);
        }
#pragma unroll
        for (int et = 0; et < 2; ++et) {
            const short* wr = wkv + (size_t)(256 + (hbase + hh) * 32 + et * 16 + m) * 64 + g * 8;
            wvA[hh][et][0] = *(const bf16x8*)wr;
            wvA[hh][et][1] = *(const bf16x8*)(wr + 32);
        }
    }

    f32x4 acc[2][2][2];   // [hh][dt][et] - all static indices
#pragma unroll
    for (int hh = 0; hh < 2; ++hh)
#pragma unroll
        for (int dt = 0; dt < 2; ++dt)
#pragma unroll
            for (int et = 0; et < 2; ++et) acc[hh][dt][et] = (f32x4){0.f, 0.f, 0.f, 0.f};
    float zacc[2][2] = {{0.f, 0.f}, {0.f, 0.f}};

#pragma unroll 1
    for (int ic = 0; ic < 4; ++ic) {
        bf16x8 af[2][2];
#pragma unroll
        for (int mt = 0; mt < 2; ++mt)
#pragma unroll
            for (int kf = 0; kf < 2; ++kf) {
                int rowi = cg * 128 + ic * 32 + mt * 16 + m;
                af[mt][kf] = *(const bf16x8*)(xnz + rowi * 128 + (((kf*4+g) ^ (rowi & 7)) << 4));
            }
#pragma unroll
        for (int hh = 0; hh < 2; ++hh) {
            u32 ek[2][2][2], vv[2][2][2];
#pragma unroll
            for (int dt = 0; dt < 2; ++dt) {
#pragma unroll
                for (int mt = 0; mt < 2; ++mt) {
                    f32x4 a = {0.f, 0.f, 0.f, 0.f};
                    a = MFMA(af[mt][0], wkA[hh][dt][0], a, 0, 0, 0);
                    a = MFMA(af[mt][1], wkA[hh][dt][1], a, 0, 0, 0);
                    float e0 = __expf(a[0]), e1 = __expf(a[1]);
                    float e2 = __expf(a[2]), e3 = __expf(a[3]);
                    zacc[hh][dt] += (e0 + e1) + (e2 + e3);
                    ek[dt][mt][0] = pack2(e0, e1);
                    ek[dt][mt][1] = pack2(e2, e3);
                }
            }
#pragma unroll
            for (int et = 0; et < 2; ++et) {
#pragma unroll
                for (int mt = 0; mt < 2; ++mt) {
                    f32x4 a = {0.f, 0.f, 0.f, 0.f};
                    a = MFMA(af[mt][0], wvA[hh][et][0], a, 0, 0, 0);
                    a = MFMA(af[mt][1], wvA[hh][et][1], a, 0, 0, 0);
                    vv[et][mt][0] = pack2(a[0], a[1]);
                    vv[et][mt][1] = pack2(a[2], a[3]);
                }
            }
#pragma unroll
            for (int dt = 0; dt < 2; ++dt)
#pragma unroll
                for (int et = 0; et < 2; ++et)
#pragma unroll
                    for (int mt = 0; mt < 2; ++mt)
                        acc[hh][dt][et] = MFMA(padfrag(ek[dt][mt][0], ek[dt][mt][1]),
                                               padfrag(vv[et][mt][0], vv[et][mt][1]),
                                               acc[hh][dt][et], 0, 0, 0);
        }
    }

    // C. combine (unchanged round-8 code)
    __syncthreads();
#pragma unroll
    for (int hh = 0; hh < 2; ++hh) {
#pragma unroll
        for (int dt = 0; dt < 2; ++dt) {
#pragma unroll
            for (int et = 0; et < 2; ++et)
#pragma unroll
                for (int r4 = 0; r4 < 4; ++r4)
                    lctx[wid][hh][dt * 16 + g * 4 + r4][et * 16 + m] = acc[hh][dt][et][r4];
            float z = zacc[hh][dt];
            z += __shfl_xor(z, 16);
            z += __shfl_xor(z, 32);
            if (g == 0) lz[wid][hh][dt * 16 + m] = z;
        }
    }
    __syncthreads();

    float* P = partials + (size_t)blk * 4224;
    for (int i = tid; i < 4096; i += 256) {
        int h = i >> 10, de = i & 1023, d = de >> 5, e = de & 31;
        int w0 = h >> 1, hh2 = h & 1;
        P[i] = lctx[w0][hh2][d][e] + lctx[w0 + 2][hh2][d][e];
    }
    if (tid < 128) {
        int h = tid >> 5, d = tid & 31;
        P[4096 + tid] = lz[h >> 1][h & 1][d] + lz[(h >> 1) + 2][h & 1][d];
    }
}

// ---- ctxt stage A: reduce 432 partials/batch -> 16 groups of 27 ----
__global__ __launch_bounds__(256) void la_ctxt_a(const float* __restrict__ partials,
                                                 float* __restrict__ part2)
{
    int t = blockIdx.x * 256 + threadIdx.x;       // 2*16*4224 = 135168 exactly
    int b = t / 67584;
    int rem = t % 67584;
    int grp = rem / 4224;
    int i = rem % 4224;
    const float* P = partials + ((size_t)(b * 432 + grp * 27)) * 4224 + i;
    float s = 0.f;
#pragma unroll 3
    for (int j = 0; j < 27; ++j) s += P[(size_t)j * 4224];
    part2[((size_t)(b * 16 + grp)) * 4224 + i] = s;
}

// ---- ctxt stage B: one block per (b,h): final sum + mem_kv fold + emit ctxA frags ----
__global__ __launch_bounds__(256) void la_ctxt_b(const float* __restrict__ part2,
                                                 const float* __restrict__ mem_kv,
                                                 u32* __restrict__ ctxA)
{
    __shared__ float ctxN[32][33];
    const int tid = threadIdx.x;
    const int b = blockIdx.x >> 2, h = blockIdx.x & 3;
    const float* P = part2 + (size_t)b * 16 * 4224;
#pragma unroll
    for (int u = 0; u < 4; ++u) {
        int de = tid * 4 + u;
        int d = de >> 5, e = de & 31;
        float S = 0.f, Z = 0.f;
#pragma unroll 4
        for (int grp = 0; grp < 16; ++grp) {
            S += P[(size_t)grp * 4224 + h * 1024 + de];
            Z += P[(size_t)grp * 4224 + 4096 + h * 32 + d];
        }
        const float* mk = mem_kv + (h * 32 + d) * 4;
        const float* mv = mem_kv + 512 + (h * 32 + e) * 4;
#pragma unroll
        for (int mm = 0; mm < 4; ++mm) {
            float ekv = __expf(mk[mm]);
            S += ekv * mv[mm];
            Z += ekv;
        }
        ctxN[d][e] = S / Z;
    }
    __syncthreads();
    // emit A-frag layout: ctxA[(b*4+h)*512 + et*256 + dt*128 + lane*2 + q]
#pragma unroll
    for (int k = 0; k < 2; ++k) {
        int j = tid * 2 + k;                  // 0..511
        int q = j & 1, lanej = (j >> 1) & 63, dt = (j >> 7) & 1, et = (j >> 8) & 1;
        int gg = lanej >> 4, mm = lanej & 15;
        int d0 = dt * 16 + gg * 4 + 2 * q, e = et * 16 + mm;
        ctxA[(size_t)(b * 4 + h) * 512 + j] = pack2(ctxN[d0][e], ctxN[d0 + 1][e]);
    }
}

// ---- pass2: round-8 numerics, 2 chunks (64 pos) per wave (mt = 0..3) to amortize
//      weight/ctx loads. Grid halves to 864 blocks. ----
__global__ __launch_bounds__(256, 3) void la_pass2(
    const short* __restrict__ xnT, const short* __restrict__ wq,
    const u32* __restrict__ ctxA, const short* __restrict__ wout,
    const float* __restrict__ b_out, const float* __restrict__ g_out,
    float* __restrict__ out)
{
    const int tid = threadIdx.x, lane = tid & 63, wid = tid >> 6;
    const int g = lane >> 4, m = lane & 15;
    const int blk = blockIdx.x;
    const int batch = blk / 432;
    const int task = (blk % 432) * 4 + wid;   // [0, 1728): 64-pos tasks per batch
    const int posbase = task * 64;

    const short* xp = xnT + ((size_t)batch * NPOS + posbase) * 64;
    bf16x8 af[4][2];
#pragma unroll
    for (int mt = 0; mt < 4; ++mt)
#pragma unroll
        for (int kf = 0; kf < 2; ++kf)
            af[mt][kf] = *(const bf16x8*)(xp + (mt * 16 + m) * 64 + kf * 32 + g * 8);

    f32x4 oacc[4][4];   // [ct][mt]
#pragma unroll
    for (int ct = 0; ct < 4; ++ct)
#pragma unroll
        for (int mt = 0; mt < 4; ++mt) oacc[ct][mt] = (f32x4){0.f, 0.f, 0.f, 0.f};

    const float scale = 0.17677669529663687f;   // 32^-0.5
    const u32* cab = ctxA + (size_t)batch * 4 * 512;

#pragma unroll 1
    for (int h = 0; h < 4; ++h) {
        // EQ = exp(Wq . Xn^T): C[d][p], d on (g,r), p on m
        u32 eqB[2][4][2];   // [dt][mt][q]
        float dpart[4] = {0.f, 0.f, 0.f, 0.f};
#pragma unroll
        for (int dt = 0; dt < 2; ++dt) {
            const short* wr = wq + (size_t)(h * 32 + dt * 16 + m) * 64 + g * 8;
            bf16x8 a0 = *(const bf16x8*)wr;
            bf16x8 a1 = *(const bf16x8*)(wr + 32);
#pragma unroll
            for (int mt = 0; mt < 4; ++mt) {
                f32x4 a = {0.f, 0.f, 0.f, 0.f};
                a = MFMA(a0, af[mt][0], a, 0, 0, 0);
                a = MFMA(a1, af[mt][1], a, 0, 0, 0);
                float e0 = __expf(a[0]), e1 = __expf(a[1]);
                float e2 = __expf(a[2]), e3 = __expf(a[3]);
                dpart[mt] += (e0 + e1) + (e2 + e3);
                eqB[dt][mt][0] = pack2(e0, e1);
                eqB[dt][mt][1] = pack2(e2, e3);
            }
        }
        float inv[4];
#pragma unroll
        for (int mt = 0; mt < 4; ++mt) {
            float dn = dpart[mt];
            dn += __shfl_xor(dn, 16);
            dn += __shfl_xor(dn, 32);
            inv[mt] = scale / dn;
        }
        // hid[e][p] = sum_d ctx[d][e]*EQ[d][p] (contract d = C-row of EQ)
        u32 hidB[2][4][2];  // [et][mt][q]
#pragma unroll
        for (int et = 0; et < 2; ++et) {
            u32x2 c0 = *(const u32x2*)(cab + h * 512 + et * 256 + 0 * 128 + lane * 2);
            u32x2 c1 = *(const u32x2*)(cab + h * 512 + et * 256 + 1 * 128 + lane * 2);
#pragma unroll
            for (int mt = 0; mt < 4; ++mt) {
                f32x4 hh2 = {0.f, 0.f, 0.f, 0.f};
                hh2 = MFMA(padfrag(c0.x, c0.y), padfrag(eqB[0][mt][0], eqB[0][mt][1]), hh2, 0, 0, 0);
                hh2 = MFMA(padfrag(c1.x, c1.y), padfrag(eqB[1][mt][0], eqB[1][mt][1]), hh2, 0, 0, 0);
                hidB[et][mt][0] = pack2(hh2[0] * inv[mt], hh2[1] * inv[mt]);
                hidB[et][mt][1] = pack2(hh2[2] * inv[mt], hh2[3] * inv[mt]);
            }
        }
        // out[c][p] += sum_e wout[c][e]*hid[e][p] (contract e = C-row of hid)
#pragma unroll
        for (int ct = 0; ct < 4; ++ct)
#pragma unroll
            for (int et = 0; et < 2; ++et) {
                u32x2 wv = *(const u32x2*)(wout + (size_t)(ct * 16 + m) * 128
                                           + h * 32 + et * 16 + g * 4);
                bf16x8 wfr = padfrag(wv.x, wv.y);
#pragma unroll
                for (int mt = 0; mt < 4; ++mt)
                    oacc[ct][mt] = MFMA(wfr, padfrag(hidB[et][mt][0], hidB[et][mt][1]),
                                        oacc[ct][mt], 0, 0, 0);
            }
    }

    // epilogue: +b_out, rmsnorm over c, *g_out, store (c = ct*16+g*4+r, p = posbase+mt*16+m)
    float bo[4][4], go[4][4];
#pragma unroll
    for (int ct = 0; ct < 4; ++ct)
#pragma unroll
        for (int r = 0; r < 4; ++r) {
            int c = ct * 16 + g * 4 + r;
            bo[ct][r] = b_out[c];
            go[ct][r] = g_out[c];
        }
    float* ob = out + (size_t)batch * 64 * NPOS;
#pragma unroll
    for (int mt = 0; mt < 4; ++mt) {
        float vv[4][4]; float s2 = 0.f;
#pragma unroll
        for (int ct = 0; ct < 4; ++ct)
#pragma unroll
            for (int r = 0; r < 4; ++r) {
                float v = oacc[ct][mt][r] + bo[ct][r];
                vv[ct][r] = v;
                s2 += v * v;
            }
        s2 += __shfl_xor(s2, 16);
        s2 += __shfl_xor(s2, 32);
        float rn2 = 8.0f / fmaxf(sqrtf(s2), 1e-12f);
        int pn = posbase + mt * 16 + m;
#pragma unroll
        for (int ct = 0; ct < 4; ++ct)
#pragma unroll
            for (int r = 0; r < 4; ++r)
                ob[(size_t)(ct * 16 + g * 4 + r) * NPOS + pn] = vv[ct][r] * rn2 * go[ct][r];
    }
}

extern "C" void kernel_launch(void* const* d_in, const int* in_sizes, int n_in,
                              void* d_out, int out_size, void* d_ws, size_t ws_size,
                              hipStream_t stream) {
    const float* x      = (const float*)d_in[0];
    const float* g_in   = (const float*)d_in[1];
    const float* w_qkv  = (const float*)d_in[2];
    const float* mem_kv = (const float*)d_in[3];
    const float* w_out  = (const float*)d_in[4];
    const float* b_out  = (const float*)d_in[5];
    const float* g_out  = (const float*)d_in[6];
    float* out = (float*)d_out;

    char* ws = (char*)d_ws;
    short* xnT     = (short*)(ws);                 // 28,311,552 B
    float* part2   = (float*)(ws + 28311552);      //    540,672 B (2*16*4224 f32)
    short* wqkv_bf = (short*)(ws + 28852224);      //     49,152 B
    short* wout_bf = (short*)(ws + 28901376);      //     16,384 B
    u32*   ctxA    = (u32*)  (ws + 28917760);      //     16,384 B (end ~28.9 MB)

    // p01 partials (864*4224 f32 = 14.6 MB) live in d_out scratch; fully consumed
    // by la_ctxt_a before la_pass2 overwrites d_out with the real output.
    float* partials = (float*)d_out;

    la_prep<<<96, 256, 0, stream>>>(w_qkv, g_in, w_out, wqkv_bf, wout_bf);
    la_p01<<<864, 256, 0, stream>>>(x, wqkv_bf, xnT, partials);
    la_ctxt_a<<<528, 256, 0, stream>>>(partials, part2);
    la_ctxt_b<<<8, 256, 0, stream>>>(part2, mem_kv, ctxA);
    la_pass2<<<864, 256, 0, stream>>>(xnT, wqkv_bf, ctxA, wout_bf, b_out, g_out, out);
}